// Round 12
// baseline (4591.311 us; speedup 1.0000x reference)
//
#include <hip/hip_runtime.h>
#include <hip/hip_bf16.h>

typedef __hip_bfloat16 bf16;
typedef __attribute__((ext_vector_type(4))) float f32x4;
typedef __attribute__((ext_vector_type(8))) short bf16x8;
typedef unsigned long long u64;
typedef unsigned short u16;
typedef unsigned u32;

#define T_STEPS 512
#define BATCH   32
#define DIM     1024
#define HID     1024
#define GATES   4096
#define NPROD   64    // producer blocks: 2 halves x 32, 512 threads
#define NOWN    32    // owner blocks: 1 per batch, 512 threads
#define NBLK    (NPROD + NOWN)

static __device__ __forceinline__ float sigmf(float x) {
    return 1.0f / (1.0f + __expf(-x));
}
// overflow-safe tanh via exp: +/-inf exp -> correct +/-1, no NaN
static __device__ __forceinline__ float tanhfast(float x) {
    return 1.0f - 2.0f / (__expf(2.0f * x) + 1.0f);
}

// coherent (LLC-level) helpers: relaxed agent atomics -> sc-qualified ops,
// no cache-wide fences; L1/L2 stay warm for Wh/gx.
static __device__ __forceinline__ u64 ldc_u64(const u64* p) {
    return __hip_atomic_load((u64*)p, __ATOMIC_RELAXED, __HIP_MEMORY_SCOPE_AGENT);
}
static __device__ __forceinline__ void stc_u64(u64* p, u64 v) {
    __hip_atomic_store(p, v, __ATOMIC_RELAXED, __HIP_MEMORY_SCOPE_AGENT);
}
static __device__ __forceinline__ void stc_u32(u32* p, u32 v) {
    __hip_atomic_store(p, v, __ATOMIC_RELAXED, __HIP_MEMORY_SCOPE_AGENT);
}
static __device__ __forceinline__ u32 ldc_u32(const u32* p) {
    return __hip_atomic_load((u32*)p, __ATOMIC_RELAXED, __HIP_MEMORY_SCOPE_AGENT);
}

// ---------------------------------------------------------------- prep ----
// hraw = packed bf16(h0) pairs; sent/gpart/gates_u cleared (stale tags die
// across graph replays). Runs before scan every launch (stream-ordered).
__global__ void prep_kernel(const float* __restrict__ input,
                            const float* __restrict__ Wx,
                            const float* __restrict__ Wh,
                            const float* __restrict__ h0,
                            bf16* __restrict__ input_b,
                            bf16* __restrict__ Wx_b,
                            bf16* __restrict__ Wh_b,
                            u32* __restrict__ hraw,     // [B][512] packed pairs
                            u32* __restrict__ sent,     // [B] stride 16
                            u64* __restrict__ gpart,    // [B][64]
                            u64* __restrict__ gates_u) {
    const size_t NIN = (size_t)T_STEPS * BATCH * DIM;
    const size_t NW  = (size_t)GATES * DIM;
    const size_t NH2 = (size_t)BATCH * 512;
    const size_t NG  = (size_t)BATCH * GATES;
    const size_t stride = (size_t)gridDim.x * blockDim.x;
    const size_t t0 = (size_t)blockIdx.x * blockDim.x + threadIdx.x;
    for (size_t i = t0; i < NIN; i += stride) input_b[i] = __float2bfloat16(input[i]);
    for (size_t i = t0; i < NW;  i += stride) Wx_b[i]    = __float2bfloat16(Wx[i]);
    for (size_t i = t0; i < NW;  i += stride) Wh_b[i]    = __float2bfloat16(Wh[i]);
    for (size_t i = t0; i < NH2; i += stride) {
        u32 lo = (u32)__bfloat16_as_ushort(__float2bfloat16(h0[2 * i]));
        u32 hi = (u32)__bfloat16_as_ushort(__float2bfloat16(h0[2 * i + 1]));
        hraw[i] = lo | (hi << 16);
    }
    for (size_t i = t0; i < 512;  i += stride) sent[i] = 0u;
    for (size_t i = t0; i < 2048; i += stride) gpart[i] = 0;
    for (size_t i = t0; i < NG;   i += stride) gates_u[i] = 0;
}

// ------------------------------------------------- big GEMM: gates_x -----
__global__ __launch_bounds__(256) void gemm_input(const bf16* __restrict__ A,
                                                  const bf16* __restrict__ W,
                                                  bf16* __restrict__ C) {
    const int bn = blockIdx.x & 31;
    const int bm = blockIdx.x >> 5;
    const int lane = threadIdx.x & 63;
    const int w = threadIdx.x >> 6;
    const int wm = (w >> 1) * 64, wn = (w & 1) * 64;
    const int lr = lane & 15;
    const int ko = (lane >> 4) * 8;

    const bf16* Abase = A + (size_t)(bm * 128 + wm + lr) * DIM + ko;
    const bf16* Wbase = W + (size_t)(bn * 128 + wn + lr) * DIM + ko;

    f32x4 acc[4][4] = {};
    for (int k = 0; k < DIM; k += 32) {
        bf16x8 af[4], bw[4];
#pragma unroll
        for (int m = 0; m < 4; ++m)
            af[m] = *(const bf16x8*)(Abase + (size_t)m * 16 * DIM + k);
#pragma unroll
        for (int n = 0; n < 4; ++n)
            bw[n] = *(const bf16x8*)(Wbase + (size_t)n * 16 * DIM + k);
#pragma unroll
        for (int m = 0; m < 4; ++m)
#pragma unroll
            for (int n = 0; n < 4; ++n)
                acc[m][n] = __builtin_amdgcn_mfma_f32_16x16x32_bf16(af[m], bw[n], acc[m][n], 0, 0, 0);
    }
    const int cr = (lane >> 4) * 4;
#pragma unroll
    for (int m = 0; m < 4; ++m)
#pragma unroll
        for (int n = 0; n < 4; ++n)
#pragma unroll
            for (int r = 0; r < 4; ++r) {
                int row = bm * 128 + wm + m * 16 + cr + r;
                int col = bn * 128 + wn + n * 16 + lr;
                C[(size_t)row * GATES + col] = __float2bfloat16(acc[m][n][r]);
            }
}

// -------------------------------------------------- persistent scan ------
// Heterogeneous 96-block grid (dataflow sync):
//  producers 0..63: poll h sentinel -> raw-stage LDS -> MFMA -> publish
//    tagged gate values -> reduce+publish tagged per-row LN partials.
//  owners 64..95 (one per batch): wave0 polls 64 partial words -> mu/rstd;
//    other waves poll gate values; 1 sync; cell; c block-reduce; raw h
//    publish + drain + sentinel; deferred NT out.
__global__ __launch_bounds__(512, 2) void scan_kernel(
    const bf16* __restrict__ gx,        // [T][B][4096] bf16
    const bf16* __restrict__ Wh_b,      // [4096][1024] bf16
    const float* __restrict__ c0,
    const float* __restrict__ gn_g, const float* __restrict__ gn_b,
    const float* __restrict__ cn_g, const float* __restrict__ cn_b,
    u32* __restrict__ hraw,             // [B][512] raw packed h (coherent)
    u32* __restrict__ sent,             // [B] sentinels, stride 16
    u64* __restrict__ gpart,            // [B][64] tagged LN partials
    u64* __restrict__ gates_u,          // [B][4096] tagged gates (coherent)
    float* __restrict__ out,
    float* __restrict__ h_final,
    float* __restrict__ c_final) {

    const int tid  = threadIdx.x;
    const int lane = tid & 63;
    const int w    = tid >> 6;           // 0..7

    if (blockIdx.x < NPROD) {
        // ======================= PRODUCER BLOCK =======================
        const int mi   = blockIdx.x & 1;     // batch half: rows mi*16..+16
        const int g    = blockIdx.x >> 1;    // 0..31: gate cols [g*128, +128)
        const int ni   = g * 8 + w;          // this wave's 16-col tile
        const int lr   = lane & 15;
        const int hi   = lane >> 4;
        const int ko   = hi * 8;
        const int cr   = hi * 4;
        const int gcol = ni * 16 + lr;
        const int brow = mi * 16 + cr;

        __shared__ __align__(16) char hsm[16 * 2048];  // 16 x 1024 bf16, swizzled
        __shared__ float pr[8][16][2];                 // per-wave row partials

        // persist this wave's Wh slice (16 cols x 1024 K) in VGPRs
        const bf16* wbase = Wh_b + (size_t)gcol * HID + ko;
        bf16x8 bfrag[32];
#pragma unroll
        for (int kk = 0; kk < 32; ++kk)
            bfrag[kk] = *(const bf16x8*)(wbase + kk * 32);

        const int arow = lr * 2048;
        const int axor = (lr & 7) << 4;

        // gx prefetch for t=0
        const u16* gxp0 = (const u16*)gx + ((size_t)brow * GATES + gcol);
        u16 gxu[4];
#pragma unroll
        for (int r = 0; r < 4; ++r)
            gxu[r] = __builtin_nontemporal_load(gxp0 + (size_t)r * GATES);

        for (int t = 0; t < T_STEPS; ++t) {
            // ---- stage h: half-wave polls row sentinel then raw-loads ----
            {
                const int row0 = 2 * w + (lane >> 5);
                const int l5 = lane & 31;
                u32 sv = ldc_u32(sent + (mi * 16 + row0) * 16);
                while (!__all((int)(sv >= (u32)t))) {
                    __builtin_amdgcn_s_sleep(1);
                    sv = ldc_u32(sent + (mi * 16 + row0) * 16);
                }
                const u64* hsrc = (const u64*)(hraw + (size_t)(mi * 16 + row0) * 512);
                char* drow = hsm + row0 * 2048;
                const int sx = (row0 & 7) << 4;
#pragma unroll
                for (int k = 0; k < 8; ++k) {
                    int j = k * 32 + l5;                  // u64 granule (8B)
                    u64 v = ldc_u64(hsrc + j);
                    *(u64*)(drow + ((8 * j) ^ sx)) = v;
                }
            }
            __syncthreads();

            // ---- MFMA + tagged gate-value publish ----
            float val[4];
            {
                f32x4 acc = {0.f, 0.f, 0.f, 0.f};
#pragma unroll
                for (int kk = 0; kk < 32; ++kk) {
                    bf16x8 a = *(const bf16x8*)(hsm + arow + ((kk * 64 + ko * 2) ^ axor));
                    acc = __builtin_amdgcn_mfma_f32_16x16x32_bf16(a, bfrag[kk], acc, 0, 0, 0);
                }
                u64* gp = gates_u + (size_t)brow * GATES + gcol;
                const u64 tagup = (u64)(u32)(t + 1) << 32;
#pragma unroll
                for (int r = 0; r < 4; ++r) {
                    union { u16 u; bf16 h; } cv; cv.u = gxu[r];
                    val[r] = acc[r] + __bfloat162float(cv.h);
                    stc_u64(gp + (size_t)r * GATES, tagup | (u64)__float_as_uint(val[r]));
                }
            }

            // ---- per-row LN partials over this block's 128 cols ----
            {
                float s[4], q[4];
#pragma unroll
                for (int r = 0; r < 4; ++r) { s[r] = val[r]; q[r] = val[r] * val[r]; }
#pragma unroll
                for (int m = 1; m <= 8; m <<= 1)
#pragma unroll
                    for (int r = 0; r < 4; ++r) {
                        s[r] += __shfl_xor(s[r], m, 64);
                        q[r] += __shfl_xor(q[r], m, 64);
                    }
                if (lr == 0)
#pragma unroll
                    for (int r = 0; r < 4; ++r) {
                        pr[w][cr + r][0] = s[r];
                        pr[w][cr + r][1] = q[r];
                    }
            }
            __syncthreads();
            if (tid < 32) {
                int row = tid >> 1, which = tid & 1;
                float v = 0.f;
#pragma unroll
                for (int ww = 0; ww < 8; ++ww) v += pr[ww][row][which];
                stc_u64(gpart + (size_t)(mi * 16 + row) * 64 + 2 * g + which,
                        ((u64)(u32)(t + 1) << 32) | (u64)__float_as_uint(v));
            }

            // ---- prefetch gx(t+1) (overlaps next h-poll) ----
            if (t + 1 < T_STEPS) {
                const u16* gxt = gxp0 + (size_t)(t + 1) * (BATCH * GATES);
#pragma unroll
                for (int r = 0; r < 4; ++r)
                    gxu[r] = __builtin_nontemporal_load(gxt + (size_t)r * GATES);
            }
            // no end barrier: dataflow (next sentinel) subsumes it
        }
        return;
    }

    // ========================== OWNER BLOCK ==========================
    const int b = blockIdx.x - NPROD;     // batch 0..31
    __shared__ float red[2][8];
    __shared__ float musd[2];

    float creg[2];
#pragma unroll
    for (int q = 0; q < 2; ++q) creg[q] = c0[b * HID + 2 * tid + q];

    for (int t = 0; t < T_STEPS; ++t) {
        const u32 want = (u32)(t + 1);

        // ---- wave0: poll 64 tagged partial words -> mu/rstd ----
        if (w == 0) {
            const u64* pp = gpart + (size_t)b * 64;
            u64 pv = ldc_u64(pp + lane);
            while (!__all((int)((u32)(pv >> 32) == want))) {
                __builtin_amdgcn_s_sleep(1);
                pv = ldc_u64(pp + lane);
            }
            float pay = __uint_as_float((u32)pv);
            float sv = (lane & 1) ? 0.f : pay;
            float qv = (lane & 1) ? pay : 0.f;
#pragma unroll
            for (int m = 1; m <= 32; m <<= 1) {
                sv += __shfl_xor(sv, m, 64);
                qv += __shfl_xor(qv, m, 64);
            }
            if (lane == 0) {
                float mu = sv * (1.0f / GATES);
                musd[0] = mu;
                musd[1] = rsqrtf(qv * (1.0f / GATES) - mu * mu + 1e-5f);
            }
        }

        // ---- all waves: poll own tagged gate values ----
        const u64* grow = gates_u + (size_t)b * GATES;
        u64 vg[4][2];
#pragma unroll
        for (int q = 0; q < 4; ++q)
#pragma unroll
            for (int e = 0; e < 2; ++e)
                vg[q][e] = ldc_u64(grow + q * 1024 + 2 * tid + e);
        for (;;) {
            bool ok = true;
#pragma unroll
            for (int q = 0; q < 4; ++q)
#pragma unroll
                for (int e = 0; e < 2; ++e)
                    if ((u32)(vg[q][e] >> 32) != want) {
                        ok = false;
                        vg[q][e] = ldc_u64(grow + q * 1024 + 2 * tid + e);
                    }
            if (ok) break;
            __builtin_amdgcn_s_sleep(1);
        }
        __syncthreads();   // musd visible; all values in registers
        const float mu   = musd[0];
        const float rstd = musd[1];

        // ---- cell + c partial ----
        float ov[2], cn_[2];
        float cs = 0.f, cs2 = 0.f;
#pragma unroll
        for (int q = 0; q < 2; ++q) {
            int j = 2 * tid + q;
            float gi = __uint_as_float((u32)vg[0][q]);
            float gf = __uint_as_float((u32)vg[1][q]);
            float gg = __uint_as_float((u32)vg[2][q]);
            float go = __uint_as_float((u32)vg[3][q]);
            float iv = sigmf(   (gi - mu) * rstd * gn_g[j]           + gn_b[j]);
            float fv = sigmf(   (gf - mu) * rstd * gn_g[HID + j]     + gn_b[HID + j]);
            float gv = tanhfast((gg - mu) * rstd * gn_g[2 * HID + j] + gn_b[2 * HID + j]);
            ov[q] =             (go - mu) * rstd * gn_g[3 * HID + j] + gn_b[3 * HID + j];
            float cnew = fv * creg[q] + iv * gv;
            cn_[q] = cnew;
            cs += cnew; cs2 += cnew * cnew;
        }
#pragma unroll
        for (int off = 32; off > 0; off >>= 1) {
            cs  += __shfl_down(cs, off, 64);
            cs2 += __shfl_down(cs2, off, 64);
        }
        if (lane == 0) { red[0][w] = cs; red[1][w] = cs2; }
        __syncthreads();
        cs  = red[0][0] + red[0][1] + red[0][2] + red[0][3]
            + red[0][4] + red[0][5] + red[0][6] + red[0][7];
        cs2 = red[1][0] + red[1][1] + red[1][2] + red[1][3]
            + red[1][4] + red[1][5] + red[1][6] + red[1][7];
        const float mu2   = cs * (1.0f / HID);
        const float rstd2 = rsqrtf(cs2 * (1.0f / HID) - mu2 * mu2 + 1e-5f);

        // ---- c-LN, h; raw publish -> drain -> sentinel ----
        float hv_[2];
#pragma unroll
        for (int q = 0; q < 2; ++q) {
            float cn = (cn_[q] - mu2) * rstd2 * cn_g[2 * tid + q] + cn_b[2 * tid + q];
            creg[q] = cn;
            hv_[q] = sigmf(ov[q]) * tanhfast(cn);
        }
        u32 hp = (u32)__bfloat16_as_ushort(__float2bfloat16(hv_[0])) |
                 ((u32)__bfloat16_as_ushort(__float2bfloat16(hv_[1])) << 16);
        stc_u32(hraw + (size_t)b * 512 + tid, hp);
        asm volatile("s_waitcnt vmcnt(0)" ::: "memory");
        __syncthreads();   // all waves' raw stores LLC-acked
        if (tid == 0) stc_u32(sent + b * 16, want);

        // deferred: out (NT) and finals -- off the critical path
        float* orow = out + ((size_t)t * BATCH + b) * HID + 2 * tid;
#pragma unroll
        for (int q = 0; q < 2; ++q)
            __builtin_nontemporal_store(hv_[q], orow + q);
        if (t == T_STEPS - 1) {
#pragma unroll
            for (int q = 0; q < 2; ++q) {
                h_final[b * HID + 2 * tid + q] = hv_[q];
                c_final[b * HID + 2 * tid + q] = creg[q];
            }
        }
    }
}

// ----------------------------------------------------------- launcher ----
extern "C" void kernel_launch(void* const* d_in, const int* in_sizes, int n_in,
                              void* d_out, int out_size, void* d_ws, size_t ws_size,
                              hipStream_t stream) {
    const float* input = (const float*)d_in[0];
    const float* h0    = (const float*)d_in[1];
    const float* c0    = (const float*)d_in[2];
    const float* Wx    = (const float*)d_in[3];
    const float* Wh    = (const float*)d_in[4];
    const float* gn_g  = (const float*)d_in[5];
    const float* gn_b  = (const float*)d_in[6];
    const float* cn_g  = (const float*)d_in[7];
    const float* cn_b  = (const float*)d_in[8];

    char* ws = (char*)d_ws;
    size_t off = 0;
    auto alloc = [&](size_t bytes) -> char* {
        char* p = ws + off;
        off += (bytes + 255) & ~(size_t)255;
        return p;
    };
    bf16* input_b = (bf16*)alloc((size_t)T_STEPS * BATCH * DIM * 2);
    bf16* Wx_b    = (bf16*)alloc((size_t)GATES * DIM * 2);
    bf16* Wh_b    = (bf16*)alloc((size_t)GATES * DIM * 2);
    bf16* gates_x = (bf16*)alloc((size_t)T_STEPS * BATCH * GATES * 2);
    u64*  gates_u = (u64*) alloc((size_t)BATCH * GATES * 8);   // tagged gates
    u32*  hraw    = (u32*) alloc((size_t)BATCH * 512 * 4);     // raw packed h
    u32*  sentb   = (u32*) alloc(512 * 4);                     // sentinels
    u64*  gpart   = (u64*) alloc(2048 * 8);                    // tagged partials

    float* outp    = (float*)d_out;
    float* h_final = outp + (size_t)T_STEPS * BATCH * HID;
    float* c_final = h_final + (size_t)BATCH * HID;

    hipLaunchKernelGGL(prep_kernel, dim3(2048), dim3(256), 0, stream,
                       input, Wx, Wh, h0, input_b, Wx_b, Wh_b,
                       hraw, sentb, gpart, gates_u);

    hipLaunchKernelGGL(gemm_input, dim3(4096), dim3(256), 0, stream,
                       input_b, Wx_b, gates_x);

    hipLaunchKernelGGL(scan_kernel, dim3(NBLK), dim3(512), 0, stream,
                       gates_x, Wh_b, c0, gn_g, gn_b, cn_g, cn_b,
                       hraw, sentb, gpart, gates_u, outp, h_final, c_final);
}

// Round 13
// 3817.625 us; speedup vs baseline: 1.2027x; 1.2027x over previous
//
#include <hip/hip_runtime.h>
#include <hip/hip_bf16.h>

typedef __hip_bfloat16 bf16;
typedef __attribute__((ext_vector_type(4))) float f32x4;
typedef __attribute__((ext_vector_type(8))) short bf16x8;
typedef unsigned long long u64;
typedef unsigned short u16;
typedef unsigned u32;

#define T_STEPS 512
#define BATCH   32
#define DIM     1024
#define HID     1024
#define GATES   4096
#define NPROD   64          // scan producer blocks (2 halves x 32)
#define NOWN    32          // scan owner blocks (1/batch)
#define NSCAN   (NPROD + NOWN)
#define MTILES  128         // gemm: 16384 rows / 128
#define NTILES  16          // gemm: 4096 cols / 256
#define NGEMM   (MTILES * NTILES)
#define MAGIC   0x5EED0001u

static __device__ __forceinline__ float sigmf(float x) {
    return 1.0f / (1.0f + __expf(-x));
}
static __device__ __forceinline__ float tanhfast(float x) {
    return 1.0f - 2.0f / (__expf(2.0f * x) + 1.0f);
}

// coherent (LLC-level) helpers
static __device__ __forceinline__ u64 ldc_u64(const u64* p) {
    return __hip_atomic_load((u64*)p, __ATOMIC_RELAXED, __HIP_MEMORY_SCOPE_AGENT);
}
static __device__ __forceinline__ void stc_u64(u64* p, u64 v) {
    __hip_atomic_store(p, v, __ATOMIC_RELAXED, __HIP_MEMORY_SCOPE_AGENT);
}
static __device__ __forceinline__ void stc_u32(u32* p, u32 v) {
    __hip_atomic_store(p, v, __ATOMIC_RELAXED, __HIP_MEMORY_SCOPE_AGENT);
}
static __device__ __forceinline__ u32 ldc_u32(const u32* p) {
    return __hip_atomic_load((u32*)p, __ATOMIC_RELAXED, __HIP_MEMORY_SCOPE_AGENT);
}

// 8 consecutive fp32 -> bf16x8 (RN, same as previous prep path)
static __device__ __forceinline__ bf16x8 cvt8(const float* p) {
    float4 x = *(const float4*)p;
    float4 y = *(const float4*)(p + 4);
    bf16x8 r;
    ((u16*)&r)[0] = __bfloat16_as_ushort(__float2bfloat16(x.x));
    ((u16*)&r)[1] = __bfloat16_as_ushort(__float2bfloat16(x.y));
    ((u16*)&r)[2] = __bfloat16_as_ushort(__float2bfloat16(x.z));
    ((u16*)&r)[3] = __bfloat16_as_ushort(__float2bfloat16(x.w));
    ((u16*)&r)[4] = __bfloat16_as_ushort(__float2bfloat16(y.x));
    ((u16*)&r)[5] = __bfloat16_as_ushort(__float2bfloat16(y.y));
    ((u16*)&r)[6] = __bfloat16_as_ushort(__float2bfloat16(y.z));
    ((u16*)&r)[7] = __bfloat16_as_ushort(__float2bfloat16(y.w));
    return r;
}

// ------------------------------------------------------------ init ----
// Clears ONLY control state (stale tags/sentinels die across replays and
// first-call garbage is neutralized). gxT itself needs no clear: sentinels
// gate it, and its content is replay-invariant.
__global__ void init_kernel(u32* __restrict__ hx,
                            u64* __restrict__ gates_u,
                            u32* __restrict__ gxsent) {
    const size_t stride = (size_t)gridDim.x * blockDim.x;
    const size_t t0 = (size_t)blockIdx.x * blockDim.x + threadIdx.x;
    for (size_t i = t0; i < (size_t)BATCH * HID; i += stride) hx[i] = 0xFFFFFFFFu;
    for (size_t i = t0; i < (size_t)BATCH * GATES; i += stride) gates_u[i] = 0;
    for (size_t i = t0; i < (size_t)MTILES * NTILES; i += stride) gxsent[i] = 0u;
}

// ------------------------------------------------------ fused kernel ----
// blocks 0..63   : scan producers (r11 path; Wh self-converted to VGPRs;
//                  gx via per-tile sentinel + one ldc_u64 from gxT)
// blocks 64..95  : scan owners (r11 path; h0/c0 read fp32; tagged-h0 startup)
// blocks 96..2143: gemm tiles 128x256, M-major blockIdx (early t first),
//                  fp32 A/B converted in-register, C stored transposed
//                  (gxT[col][row]) via coherent u64, then drain + sentinel.
__global__ __launch_bounds__(512, 2) void fused_kernel(
    const float* __restrict__ input,    // [T*B][1024] fp32
    const float* __restrict__ Wx,       // [4096][1024] fp32
    const float* __restrict__ Wh,       // [4096][1024] fp32
    const float* __restrict__ h0,
    const float* __restrict__ c0,
    const float* __restrict__ gn_g, const float* __restrict__ gn_b,
    const float* __restrict__ cn_g, const float* __restrict__ cn_b,
    u32* __restrict__ hx,               // [B][HID] tagged h (coherent)
    u64* __restrict__ gates_u,          // [B][4096] tagged gates (coherent)
    bf16* __restrict__ gxT,             // [4096 cols][16384 rows] transposed
    u32* __restrict__ gxsent,           // [128][16] tile sentinels
    float* __restrict__ out,
    float* __restrict__ h_final,
    float* __restrict__ c_final) {

    const int tid  = threadIdx.x;
    const int lane = tid & 63;
    const int w    = tid >> 6;           // 0..7

    if (blockIdx.x >= NSCAN) {
        // ========================= GEMM BLOCK =========================
        const int gid = blockIdx.x - NSCAN;
        const int bm = gid >> 4;         // M-major: low blockIdx = low t
        const int bn = gid & 15;
        const int wm = (w >> 2) * 64, wn = (w & 3) * 64;
        const int lr = lane & 15;
        const int ko = (lane >> 4) * 8;

        const float* Af = input + (size_t)(bm * 128 + wm + lr) * DIM + ko;
        const float* Bf = Wx    + (size_t)(bn * 256 + wn + lr) * DIM + ko;

        f32x4 acc[4][4] = {};
        for (int k = 0; k < DIM; k += 32) {
            bf16x8 af[4], bw[4];
#pragma unroll
            for (int m = 0; m < 4; ++m)
                af[m] = cvt8(Af + (size_t)m * 16 * DIM + k);
#pragma unroll
            for (int n = 0; n < 4; ++n)
                bw[n] = cvt8(Bf + (size_t)n * 16 * DIM + k);
#pragma unroll
            for (int m = 0; m < 4; ++m)
#pragma unroll
                for (int n = 0; n < 4; ++n)
                    acc[m][n] = __builtin_amdgcn_mfma_f32_16x16x32_bf16(af[m], bw[n], acc[m][n], 0, 0, 0);
        }
        const int cr = (lane >> 4) * 4;
        u64* gxT64 = (u64*)gxT;
#pragma unroll
        for (int m = 0; m < 4; ++m)
#pragma unroll
            for (int n = 0; n < 4; ++n) {
                int col = bn * 256 + wn + n * 16 + lr;
                int rb  = bm * 128 + wm + m * 16 + cr;   // 4-aligned
                u64 pk = 0;
#pragma unroll
                for (int r = 0; r < 4; ++r)
                    pk |= (u64)__bfloat16_as_ushort(__float2bfloat16(acc[m][n][r])) << (16 * r);
                stc_u64(gxT64 + (size_t)col * 4096 + (rb >> 2), pk);
            }
        asm volatile("s_waitcnt vmcnt(0)" ::: "memory");
        __syncthreads();                 // all tile stores LLC-acked
        if (tid == 0) stc_u32(gxsent + bm * NTILES + bn, MAGIC);
        return;
    }

    if (blockIdx.x < NPROD) {
        // ======================= PRODUCER BLOCK =======================
        const int mi   = blockIdx.x & 1;     // batch half: rows mi*16..+16
        const int g    = blockIdx.x >> 1;    // 0..31: gate cols [g*128, +128)
        const int ni   = g * 8 + w;          // this wave's 16-col tile
        const int lr   = lane & 15;
        const int hi   = lane >> 4;
        const int ko   = hi * 8;
        const int cr   = hi * 4;
        const int gcol = ni * 16 + lr;
        const int brow = mi * 16 + cr;

        __shared__ __align__(16) char hsm[16 * 2048];  // 16 x 1024 bf16, swizzled

        // self-convert this wave's Wh slice (16 cols x 1024 K) into VGPRs
        const float* wf = Wh + (size_t)gcol * DIM + ko;
        bf16x8 bfrag[32];
#pragma unroll
        for (int kk = 0; kk < 32; ++kk)
            bfrag[kk] = cvt8(wf + kk * 32);

        const int arow = lr * 2048;
        const int axor = (lr & 7) << 4;

        const u64* gxT64 = (const u64*)gxT;
        const int ntile = g >> 1;
        u16 gxu[4];
        // gx fetch for step t: sentinel then one u64 (rows brow..brow+3, col gcol)
        {
            int mtile = (2 * 0 + mi) >> 3;
            u32 sv = ldc_u32(gxsent + mtile * NTILES + ntile);
            while (sv != MAGIC) {
                __builtin_amdgcn_s_sleep(2);
                sv = ldc_u32(gxsent + mtile * NTILES + ntile);
            }
            u64 v = ldc_u64(gxT64 + (size_t)gcol * 4096 + 0 * 8 + mi * 4 + hi);
            gxu[0] = (u16)v; gxu[1] = (u16)(v >> 16);
            gxu[2] = (u16)(v >> 32); gxu[3] = (u16)(v >> 48);
        }

        for (int t = 0; t < T_STEPS; ++t) {
            // ---- stage h: half-wave polls+stages its row (tag == t) ----
            {
                const int row0 = 2 * w + (lane >> 5);
                const int l5 = lane & 31;
                const u64* hsrc = (const u64*)(hx + (size_t)(mi * 16 + row0) * HID);
                char* drow = hsm + row0 * 2048;
                const int sx = (row0 & 7) << 4;
                const u32 want = (u32)t;
                u64 vv[16];
#pragma unroll
                for (int k = 0; k < 16; ++k)
                    vv[k] = ldc_u64(hsrc + k * 32 + l5);
                for (;;) {
                    bool ok = true;
#pragma unroll
                    for (int k = 0; k < 16; ++k) {
                        if ((((u32)(vv[k] >> 16) & 0xFFFFu) != want) ||
                            ((u32)(vv[k] >> 48) != want)) {
                            ok = false;
                            vv[k] = ldc_u64(hsrc + k * 32 + l5);
                        }
                    }
                    if (ok) break;
                    __builtin_amdgcn_s_sleep(1);
                }
#pragma unroll
                for (int k = 0; k < 16; ++k) {
                    int j = k * 32 + l5;
                    u32 packed = (u32)(vv[k] & 0xFFFFu) |
                                 (((u32)(vv[k] >> 32) & 0xFFFFu) << 16);
                    *(u32*)(drow + ((4 * j) ^ sx)) = packed;
                }
            }
            __syncthreads();

            // ---- MFMA + tagged gates publish (self-flagging) ----
            {
                f32x4 acc = {0.f, 0.f, 0.f, 0.f};
#pragma unroll
                for (int kk = 0; kk < 32; ++kk) {
                    bf16x8 a = *(const bf16x8*)(hsm + arow + ((kk * 64 + ko * 2) ^ axor));
                    acc = __builtin_amdgcn_mfma_f32_16x16x32_bf16(a, bfrag[kk], acc, 0, 0, 0);
                }
                u64* gp = gates_u + (size_t)brow * GATES + gcol;
                const u64 tagup = (u64)(u32)(t + 1) << 32;
#pragma unroll
                for (int r = 0; r < 4; ++r) {
                    union { u16 u; bf16 h; } cv; cv.u = gxu[r];
                    float val = acc[r] + __bfloat162float(cv.h);
                    stc_u64(gp + (size_t)r * GATES, tagup | (u64)__float_as_uint(val));
                }
            }

            // ---- prefetch gx(t+1) (overlaps next h-poll) ----
            if (t + 1 < T_STEPS) {
                int tn = t + 1;
                int mtile = (2 * tn + mi) >> 3;
                u32 sv = ldc_u32(gxsent + mtile * NTILES + ntile);
                while (sv != MAGIC) {
                    __builtin_amdgcn_s_sleep(2);
                    sv = ldc_u32(gxsent + mtile * NTILES + ntile);
                }
                u64 v = ldc_u64(gxT64 + (size_t)gcol * 4096 + tn * 8 + mi * 4 + hi);
                gxu[0] = (u16)v; gxu[1] = (u16)(v >> 16);
                gxu[2] = (u16)(v >> 32); gxu[3] = (u16)(v >> 48);
            }
            // no end barrier: dataflow (h(t+1) tags) subsumes it
        }
        return;
    }

    // ========================== OWNER BLOCK ==========================
    const int b = blockIdx.x - NPROD;     // batch 0..31
    __shared__ float red[2][8];

    float creg[2];
#pragma unroll
    for (int q = 0; q < 2; ++q) creg[q] = c0[b * HID + 2 * tid + q];

    // startup: publish tagged h0 (tag 0) -- self-flagging, init left 0xFFFF
    {
        u32 e0 = (u32)__bfloat16_as_ushort(__float2bfloat16(h0[b * HID + 2 * tid]));
        u32 e1 = (u32)__bfloat16_as_ushort(__float2bfloat16(h0[b * HID + 2 * tid + 1]));
        stc_u64((u64*)(hx + (size_t)b * HID + 2 * tid), (u64)e0 | ((u64)e1 << 32));
    }

    for (int t = 0; t < T_STEPS; ++t) {
        // ---- poll own tagged gates direct-to-register ----
        const u64* grow = gates_u + (size_t)b * GATES;
        const u32 want = (u32)(t + 1);
        u64 vg[4][2];
#pragma unroll
        for (int q = 0; q < 4; ++q)
#pragma unroll
            for (int e = 0; e < 2; ++e)
                vg[q][e] = ldc_u64(grow + q * 1024 + 2 * tid + e);
        for (;;) {
            bool ok = true;
#pragma unroll
            for (int q = 0; q < 4; ++q)
#pragma unroll
                for (int e = 0; e < 2; ++e)
                    if ((u32)(vg[q][e] >> 32) != want) {
                        ok = false;
                        vg[q][e] = ldc_u64(grow + q * 1024 + 2 * tid + e);
                    }
            if (ok) break;
            __builtin_amdgcn_s_sleep(1);
        }
        float gv[4][2];
        float s = 0.f, s2 = 0.f;
#pragma unroll
        for (int q = 0; q < 4; ++q)
#pragma unroll
            for (int e = 0; e < 2; ++e) {
                float x = __uint_as_float((u32)vg[q][e]);
                gv[q][e] = x;
                s += x; s2 += x * x;
            }
#pragma unroll
        for (int off = 32; off > 0; off >>= 1) {
            s  += __shfl_down(s, off, 64);
            s2 += __shfl_down(s2, off, 64);
        }
        if (lane == 0) { red[0][w] = s; red[1][w] = s2; }
        __syncthreads();
        s  = red[0][0] + red[0][1] + red[0][2] + red[0][3]
           + red[0][4] + red[0][5] + red[0][6] + red[0][7];
        s2 = red[1][0] + red[1][1] + red[1][2] + red[1][3]
           + red[1][4] + red[1][5] + red[1][6] + red[1][7];
        const float mu   = s * (1.0f / GATES);
        const float rstd = rsqrtf(s2 * (1.0f / GATES) - mu * mu + 1e-5f);

        float ov[2], cn_[2];
        float cs = 0.f, cs2 = 0.f;
#pragma unroll
        for (int q = 0; q < 2; ++q) {
            int j = 2 * tid + q;
            float iv = sigmf(   (gv[0][q] - mu) * rstd * gn_g[j]           + gn_b[j]);
            float fv = sigmf(   (gv[1][q] - mu) * rstd * gn_g[HID + j]     + gn_b[HID + j]);
            float gg = tanhfast((gv[2][q] - mu) * rstd * gn_g[2 * HID + j] + gn_b[2 * HID + j]);
            ov[q] =             (gv[3][q] - mu) * rstd * gn_g[3 * HID + j] + gn_b[3 * HID + j];
            float cnew = fv * creg[q] + iv * gg;
            cn_[q] = cnew;
            cs += cnew; cs2 += cnew * cnew;
        }
#pragma unroll
        for (int off = 32; off > 0; off >>= 1) {
            cs  += __shfl_down(cs, off, 64);
            cs2 += __shfl_down(cs2, off, 64);
        }
        __syncthreads();   // red reuse
        if (lane == 0) { red[0][w] = cs; red[1][w] = cs2; }
        __syncthreads();
        cs  = red[0][0] + red[0][1] + red[0][2] + red[0][3]
            + red[0][4] + red[0][5] + red[0][6] + red[0][7];
        cs2 = red[1][0] + red[1][1] + red[1][2] + red[1][3]
            + red[1][4] + red[1][5] + red[1][6] + red[1][7];
        const float mu2   = cs * (1.0f / HID);
        const float rstd2 = rsqrtf(cs2 * (1.0f / HID) - mu2 * mu2 + 1e-5f);

        // c-LN, h; publish tagged h immediately (self-flagging)
        float hv_[2];
        u32 he[2];
#pragma unroll
        for (int q = 0; q < 2; ++q) {
            float cn = (cn_[q] - mu2) * rstd2 * cn_g[2 * tid + q] + cn_b[2 * tid + q];
            creg[q] = cn;
            hv_[q] = sigmf(ov[q]) * tanhfast(cn);
            he[q] = ((u32)(t + 1) << 16) |
                    (u32)__bfloat16_as_ushort(__float2bfloat16(hv_[q]));
        }
        stc_u64((u64*)(hx + (size_t)b * HID + 2 * tid),
                (u64)he[0] | ((u64)he[1] << 32));

        // deferred: out (NT) and finals -- off the critical path
        float* orow = out + ((size_t)t * BATCH + b) * HID + 2 * tid;
#pragma unroll
        for (int q = 0; q < 2; ++q)
            __builtin_nontemporal_store(hv_[q], orow + q);
        if (t == T_STEPS - 1) {
#pragma unroll
            for (int q = 0; q < 2; ++q) {
                h_final[b * HID + 2 * tid + q] = hv_[q];
                c_final[b * HID + 2 * tid + q] = creg[q];
            }
        }
    }
}

// ----------------------------------------------------------- launcher ----
extern "C" void kernel_launch(void* const* d_in, const int* in_sizes, int n_in,
                              void* d_out, int out_size, void* d_ws, size_t ws_size,
                              hipStream_t stream) {
    const float* input = (const float*)d_in[0];
    const float* h0    = (const float*)d_in[1];
    const float* c0    = (const float*)d_in[2];
    const float* Wx    = (const float*)d_in[3];
    const float* Wh    = (const float*)d_in[4];
    const float* gn_g  = (const float*)d_in[5];
    const float* gn_b  = (const float*)d_in[6];
    const float* cn_g  = (const float*)d_in[7];
    const float* cn_b  = (const float*)d_in[8];

    char* ws = (char*)d_ws;
    size_t off = 0;
    auto alloc = [&](size_t bytes) -> char* {
        char* p = ws + off;
        off += (bytes + 255) & ~(size_t)255;
        return p;
    };
    u64*  gates_u = (u64*) alloc((size_t)BATCH * GATES * 8);           // 1 MB
    u32*  hx      = (u32*) alloc((size_t)BATCH * HID * 4);             // 128 KB
    u32*  gxsent  = (u32*) alloc((size_t)MTILES * NTILES * 4);         // 8 KB
    bf16* gxT     = (bf16*)alloc((size_t)GATES * (T_STEPS * BATCH) * 2); // 128 MB

    float* outp    = (float*)d_out;
    float* h_final = outp + (size_t)T_STEPS * BATCH * HID;
    float* c_final = h_final + (size_t)BATCH * HID;

    hipLaunchKernelGGL(init_kernel, dim3(256), dim3(256), 0, stream,
                       hx, gates_u, gxsent);

    hipLaunchKernelGGL(fused_kernel, dim3(NSCAN + NGEMM), dim3(512), 0, stream,
                       input, Wx, Wh, h0, c0, gn_g, gn_b, cn_g, cn_b,
                       hx, gates_u, gxT, gxsent, outp, h_final, c_final);
}

// Round 15
// 3349.558 us; speedup vs baseline: 1.3707x; 1.1397x over previous
//
#include <hip/hip_runtime.h>
#include <hip/hip_bf16.h>

typedef __hip_bfloat16 bf16;
typedef __attribute__((ext_vector_type(4))) float f32x4;
typedef __attribute__((ext_vector_type(8))) short bf16x8;
typedef unsigned long long u64;
typedef unsigned short u16;
typedef unsigned u32;

#define T_STEPS 512
#define BATCH   32
#define DIM     1024
#define HID     1024
#define GATES   4096
#define NDOM    4           // independent scan domains (8 batches each)
#define NOWN    32          // owner blocks (1/batch) -- block IDs 0..31
#define NPROD   128         // producer blocks: 4 domains x 32 colgroups
#define NSCAN   (NOWN + NPROD)   // 160 <= 256 worst-case residency
#define MTILES  128         // gemm: 16384 rows / 128
#define NTILES  16          // gemm: 4096 cols / 256
#define NGEMM   (MTILES * NTILES)
#define MAGIC   0x5EED0001u

static __device__ __forceinline__ float sigmf(float x) {
    return 1.0f / (1.0f + __expf(-x));
}
static __device__ __forceinline__ float tanhfast(float x) {
    return 1.0f - 2.0f / (__expf(2.0f * x) + 1.0f);
}

// coherent (LLC-level) helpers
static __device__ __forceinline__ u64 ldc_u64(const u64* p) {
    return __hip_atomic_load((u64*)p, __ATOMIC_RELAXED, __HIP_MEMORY_SCOPE_AGENT);
}
static __device__ __forceinline__ void stc_u64(u64* p, u64 v) {
    __hip_atomic_store(p, v, __ATOMIC_RELAXED, __HIP_MEMORY_SCOPE_AGENT);
}
static __device__ __forceinline__ void stc_u32(u32* p, u32 v) {
    __hip_atomic_store(p, v, __ATOMIC_RELAXED, __HIP_MEMORY_SCOPE_AGENT);
}
static __device__ __forceinline__ u32 ldc_u32(const u32* p) {
    return __hip_atomic_load((u32*)p, __ATOMIC_RELAXED, __HIP_MEMORY_SCOPE_AGENT);
}

// 8 consecutive fp32 -> bf16x8 (RN, same conversion as the old prep path)
static __device__ __forceinline__ bf16x8 cvt8(const float* p) {
    float4 x = *(const float4*)p;
    float4 y = *(const float4*)(p + 4);
    bf16x8 r;
    ((u16*)&r)[0] = __bfloat16_as_ushort(__float2bfloat16(x.x));
    ((u16*)&r)[1] = __bfloat16_as_ushort(__float2bfloat16(x.y));
    ((u16*)&r)[2] = __bfloat16_as_ushort(__float2bfloat16(x.z));
    ((u16*)&r)[3] = __bfloat16_as_ushort(__float2bfloat16(x.w));
    ((u16*)&r)[4] = __bfloat16_as_ushort(__float2bfloat16(y.x));
    ((u16*)&r)[5] = __bfloat16_as_ushort(__float2bfloat16(y.y));
    ((u16*)&r)[6] = __bfloat16_as_ushort(__float2bfloat16(y.z));
    ((u16*)&r)[7] = __bfloat16_as_ushort(__float2bfloat16(y.w));
    return r;
}

// ------------------------------------------------------------ init ----
// Clears ONLY control state (stale tags/sentinels die across replays).
__global__ void init_kernel(u32* __restrict__ hx,
                            u64* __restrict__ gates_u,
                            u32* __restrict__ gxsent) {
    const size_t stride = (size_t)gridDim.x * blockDim.x;
    const size_t t0 = (size_t)blockIdx.x * blockDim.x + threadIdx.x;
    for (size_t i = t0; i < (size_t)BATCH * HID; i += stride) hx[i] = 0xFFFFFFFFu;
    for (size_t i = t0; i < (size_t)BATCH * GATES; i += stride) gates_u[i] = 0;
    for (size_t i = t0; i < (size_t)MTILES * NTILES; i += stride) gxsent[i] = 0u;
}

// ------------------------------------------------------ fused kernel ----
// blocks 0..31   : scan owners (1/batch) -- FIRST in dispatch order so they
//                  are always resident (r14 deadlock fix).
// blocks 32..159 : scan producers, 4 independent domains of 8 batches
//                  (pid = bid-32; d = pid&3, g = pid>>2). Wh slice in VGPRs.
//                  Stage 8 h rows (16KB LDS, wave-per-row). MFMA A row m
//                  reads staged row m&7; hi<2 lanes publish 8 valid D rows.
// blocks 160..   : gemm tiles 128x256, M-major (early t first), fp32 in,
//                  C stored transposed via coherent u64 + tile sentinel.
// Total scan set = 160 blocks <= 256 worst-case co-residency.
__global__ __launch_bounds__(512, 2) void fused_kernel(
    const float* __restrict__ input,    // [T*B][1024] fp32
    const float* __restrict__ Wx,       // [4096][1024] fp32
    const float* __restrict__ Wh,       // [4096][1024] fp32
    const float* __restrict__ h0,
    const float* __restrict__ c0,
    const float* __restrict__ gn_g, const float* __restrict__ gn_b,
    const float* __restrict__ cn_g, const float* __restrict__ cn_b,
    u32* __restrict__ hx,               // [B][HID] tagged h (coherent)
    u64* __restrict__ gates_u,          // [B][4096] tagged gates (coherent)
    bf16* __restrict__ gxT,             // [4096 cols][16384 rows] transposed
    u32* __restrict__ gxsent,           // [128][16] tile sentinels
    float* __restrict__ out,
    float* __restrict__ h_final,
    float* __restrict__ c_final) {

    const int tid  = threadIdx.x;
    const int lane = tid & 63;
    const int w    = tid >> 6;           // 0..7

    if (blockIdx.x >= NSCAN) {
        // ========================= GEMM BLOCK =========================
        const int gid = blockIdx.x - NSCAN;
        const int bm = gid >> 4;         // M-major: low blockIdx = low t
        const int bn = gid & 15;
        const int wm = (w >> 2) * 64, wn = (w & 3) * 64;
        const int lr = lane & 15;
        const int ko = (lane >> 4) * 8;

        const float* Af = input + (size_t)(bm * 128 + wm + lr) * DIM + ko;
        const float* Bf = Wx    + (size_t)(bn * 256 + wn + lr) * DIM + ko;

        f32x4 acc[4][4] = {};
        for (int k = 0; k < DIM; k += 32) {
            bf16x8 af[4], bw[4];
#pragma unroll
            for (int m = 0; m < 4; ++m)
                af[m] = cvt8(Af + (size_t)m * 16 * DIM + k);
#pragma unroll
            for (int n = 0; n < 4; ++n)
                bw[n] = cvt8(Bf + (size_t)n * 16 * DIM + k);
#pragma unroll
            for (int m = 0; m < 4; ++m)
#pragma unroll
                for (int n = 0; n < 4; ++n)
                    acc[m][n] = __builtin_amdgcn_mfma_f32_16x16x32_bf16(af[m], bw[n], acc[m][n], 0, 0, 0);
        }
        const int cr = (lane >> 4) * 4;
        u64* gxT64 = (u64*)gxT;
#pragma unroll
        for (int m = 0; m < 4; ++m)
#pragma unroll
            for (int n = 0; n < 4; ++n) {
                int col = bn * 256 + wn + n * 16 + lr;
                int rb  = bm * 128 + wm + m * 16 + cr;   // 4-aligned
                u64 pk = 0;
#pragma unroll
                for (int r = 0; r < 4; ++r)
                    pk |= (u64)__bfloat16_as_ushort(__float2bfloat16(acc[m][n][r])) << (16 * r);
                stc_u64(gxT64 + (size_t)col * 4096 + (rb >> 2), pk);
            }
        asm volatile("s_waitcnt vmcnt(0)" ::: "memory");
        __syncthreads();                 // all tile stores LLC-acked
        if (tid == 0) stc_u32(gxsent + bm * NTILES + bn, MAGIC);
        return;
    }

    if (blockIdx.x >= NOWN) {
        // ======================= PRODUCER BLOCK =======================
        const int pid  = blockIdx.x - NOWN;
        const int d    = pid & 3;            // domain: batches 8d..8d+7
        const int g    = pid >> 2;           // 0..31: gate cols [g*128,+128)
        const int ni   = g * 8 + w;          // this wave's 16-col tile
        const int lr   = lane & 15;
        const int hi   = lane >> 4;
        const int ko   = hi * 8;
        const int gcol = ni * 16 + lr;

        __shared__ __align__(16) char hsm[8 * 2048];  // 8 rows x 1024 bf16, swizzled

        // self-convert this wave's Wh slice (16 cols x 1024 K) into VGPRs
        const float* wf = Wh + (size_t)gcol * DIM + ko;
        bf16x8 bfrag[32];
#pragma unroll
        for (int kk = 0; kk < 32; ++kk)
            bfrag[kk] = cvt8(wf + kk * 32);

        const int arow = (lr & 7) * 2048;      // A row m -> staged row m&7
        const int axor = (lr & 7) << 4;

        const u64* gxT64 = (const u64*)gxT;
        const int ntile = g >> 1;
        u16 gxu[4];
        // gx fetch for t=0: sentinel then one u64 (4 batch rows for this hi)
        {
            u32 sv = ldc_u32(gxsent + 0 * NTILES + ntile);   // rows 8d..8d+7 in tile 0
            while (sv != MAGIC) {
                __builtin_amdgcn_s_sleep(2);
                sv = ldc_u32(gxsent + 0 * NTILES + ntile);
            }
            u64 v = ldc_u64(gxT64 + (size_t)gcol * 4096 + 2 * d + (hi & 1));
            gxu[0] = (u16)v; gxu[1] = (u16)(v >> 16);
            gxu[2] = (u16)(v >> 32); gxu[3] = (u16)(v >> 48);
        }

        for (int t = 0; t < T_STEPS; ++t) {
            // ---- stage 8 h rows (tag == t): wave w stages row w ----
            {
                const u64* hsrc = (const u64*)(hx + (size_t)(8 * d + w) * HID);
                char* drow = hsm + w * 2048;
                const int sx = w << 4;
                const u32 want = (u32)t;
                u64 vv[8];
#pragma unroll
                for (int k = 0; k < 8; ++k)
                    vv[k] = ldc_u64(hsrc + k * 64 + lane);   // 8 loads in flight
                for (;;) {
                    bool ok = true;
#pragma unroll
                    for (int k = 0; k < 8; ++k) {
                        if ((((u32)(vv[k] >> 16) & 0xFFFFu) != want) ||
                            ((u32)(vv[k] >> 48) != want)) {
                            ok = false;
                            vv[k] = ldc_u64(hsrc + k * 64 + lane);
                        }
                    }
                    if (ok) break;
                    __builtin_amdgcn_s_sleep(1);
                }
#pragma unroll
                for (int k = 0; k < 8; ++k) {
                    int j = k * 64 + lane;       // pair index 0..511
                    u32 packed = (u32)(vv[k] & 0xFFFFu) |
                                 (((u32)(vv[k] >> 32) & 0xFFFFu) << 16);
                    *(u32*)(drow + ((4 * j) ^ sx)) = packed;
                }
            }
            __syncthreads();   // couples this block to only 8 owners

            // ---- MFMA (A rows duplicate mod 8) + publish 8 valid D rows ----
            {
                f32x4 acc = {0.f, 0.f, 0.f, 0.f};
#pragma unroll
                for (int kk = 0; kk < 32; ++kk) {
                    bf16x8 a = *(const bf16x8*)(hsm + arow + ((kk * 64 + ko * 2) ^ axor));
                    acc = __builtin_amdgcn_mfma_f32_16x16x32_bf16(a, bfrag[kk], acc, 0, 0, 0);
                }
                if (hi < 2) {                    // D rows 0..7 = batches 8d..8d+7
                    u64* gp = gates_u + (size_t)(8 * d + hi * 4) * GATES + gcol;
                    const u64 tagup = (u64)(u32)(t + 1) << 32;
#pragma unroll
                    for (int r = 0; r < 4; ++r) {
                        union { u16 u; bf16 h; } cv; cv.u = gxu[r];
                        float val = acc[r] + __bfloat162float(cv.h);
                        stc_u64(gp + (size_t)r * GATES, tagup | (u64)__float_as_uint(val));
                    }
                }
            }

            // ---- prefetch gx(t+1) (overlaps next h-poll) ----
            if (t + 1 < T_STEPS) {
                int tn = t + 1;
                int mtile = (4 * tn + d) >> 4;   // (tn*32 + 8d) >> 7
                u32 sv = ldc_u32(gxsent + mtile * NTILES + ntile);
                while (sv != MAGIC) {
                    __builtin_amdgcn_s_sleep(2);
                    sv = ldc_u32(gxsent + mtile * NTILES + ntile);
                }
                u64 v = ldc_u64(gxT64 + (size_t)gcol * 4096 + tn * 8 + 2 * d + (hi & 1));
                gxu[0] = (u16)v; gxu[1] = (u16)(v >> 16);
                gxu[2] = (u16)(v >> 32); gxu[3] = (u16)(v >> 48);
            }
            // no end barrier: dataflow (h(t+1) tags) subsumes it
        }
        return;
    }

    // ========================== OWNER BLOCK ==========================
    const int b = blockIdx.x;             // batch 0..31 (lowest block IDs)
    __shared__ float red[2][8];
    __shared__ float redc[2][8];          // separate buffer: saves a barrier

    float creg[2];
#pragma unroll
    for (int q = 0; q < 2; ++q) creg[q] = c0[b * HID + 2 * tid + q];

    // startup: publish tagged h0 (tag 0) -- init left 0xFFFF in tag fields
    {
        u32 e0 = (u32)__bfloat16_as_ushort(__float2bfloat16(h0[b * HID + 2 * tid]));
        u32 e1 = (u32)__bfloat16_as_ushort(__float2bfloat16(h0[b * HID + 2 * tid + 1]));
        stc_u64((u64*)(hx + (size_t)b * HID + 2 * tid), (u64)e0 | ((u64)e1 << 32));
    }

    for (int t = 0; t < T_STEPS; ++t) {
        // ---- poll own tagged gates direct-to-register ----
        const u64* grow = gates_u + (size_t)b * GATES;
        const u32 want = (u32)(t + 1);
        u64 vg[4][2];
#pragma unroll
        for (int q = 0; q < 4; ++q)
#pragma unroll
            for (int e = 0; e < 2; ++e)
                vg[q][e] = ldc_u64(grow + q * 1024 + 2 * tid + e);
        for (;;) {
            bool ok = true;
#pragma unroll
            for (int q = 0; q < 4; ++q)
#pragma unroll
            for (int e = 0; e < 2; ++e)
                if ((u32)(vg[q][e] >> 32) != want) {
                    ok = false;
                    vg[q][e] = ldc_u64(grow + q * 1024 + 2 * tid + e);
                }
            if (ok) break;
            __builtin_amdgcn_s_sleep(1);
        }
        float gv[4][2];
        float s = 0.f, s2 = 0.f;
#pragma unroll
        for (int q = 0; q < 4; ++q)
#pragma unroll
            for (int e = 0; e < 2; ++e) {
                float x = __uint_as_float((u32)vg[q][e]);
                gv[q][e] = x;
                s += x; s2 += x * x;
            }
#pragma unroll
        for (int off = 32; off > 0; off >>= 1) {
            s  += __shfl_down(s, off, 64);
            s2 += __shfl_down(s2, off, 64);
        }
        if (lane == 0) { red[0][w] = s; red[1][w] = s2; }
        __syncthreads();   // barrier 1
        s  = red[0][0] + red[0][1] + red[0][2] + red[0][3]
           + red[0][4] + red[0][5] + red[0][6] + red[0][7];
        s2 = red[1][0] + red[1][1] + red[1][2] + red[1][3]
           + red[1][4] + red[1][5] + red[1][6] + red[1][7];
        const float mu   = s * (1.0f / GATES);
        const float rstd = rsqrtf(s2 * (1.0f / GATES) - mu * mu + 1e-5f);

        float ov[2], cn_[2];
        float cs = 0.f, cs2 = 0.f;
#pragma unroll
        for (int q = 0; q < 2; ++q) {
            int j = 2 * tid + q;
            float iv = sigmf(   (gv[0][q] - mu) * rstd * gn_g[j]           + gn_b[j]);
            float fv = sigmf(   (gv[1][q] - mu) * rstd * gn_g[HID + j]     + gn_b[HID + j]);
            float gg = tanhfast((gv[2][q] - mu) * rstd * gn_g[2 * HID + j] + gn_b[2 * HID + j]);
            ov[q] =             (gv[3][q] - mu) * rstd * gn_g[3 * HID + j] + gn_b[3 * HID + j];
            float cnew = fv * creg[q] + iv * gg;
            cn_[q] = cnew;
            cs += cnew; cs2 += cnew * cnew;
        }
#pragma unroll
        for (int off = 32; off > 0; off >>= 1) {
            cs  += __shfl_down(cs, off, 64);
            cs2 += __shfl_down(cs2, off, 64);
        }
        if (lane == 0) { redc[0][w] = cs; redc[1][w] = cs2; }
        __syncthreads();   // barrier 2
        cs  = redc[0][0] + redc[0][1] + redc[0][2] + redc[0][3]
            + redc[0][4] + redc[0][5] + redc[0][6] + redc[0][7];
        cs2 = redc[1][0] + redc[1][1] + redc[1][2] + redc[1][3]
            + redc[1][4] + redc[1][5] + redc[1][6] + redc[1][7];
        const float mu2   = cs * (1.0f / HID);
        const float rstd2 = rsqrtf(cs2 * (1.0f / HID) - mu2 * mu2 + 1e-5f);

        // c-LN, h; publish tagged h immediately (self-flagging)
        float hv_[2];
        u32 he[2];
#pragma unroll
        for (int q = 0; q < 2; ++q) {
            float cn = (cn_[q] - mu2) * rstd2 * cn_g[2 * tid + q] + cn_b[2 * tid + q];
            creg[q] = cn;
            hv_[q] = sigmf(ov[q]) * tanhfast(cn);
            he[q] = ((u32)(t + 1) << 16) |
                    (u32)__bfloat16_as_ushort(__float2bfloat16(hv_[q]));
        }
        stc_u64((u64*)(hx + (size_t)b * HID + 2 * tid),
                (u64)he[0] | ((u64)he[1] << 32));

        // deferred: out (NT) and finals -- off the critical path
        float* orow = out + ((size_t)t * BATCH + b) * HID + 2 * tid;
#pragma unroll
        for (int q = 0; q < 2; ++q)
            __builtin_nontemporal_store(hv_[q], orow + q);
        if (t == T_STEPS - 1) {
#pragma unroll
            for (int q = 0; q < 2; ++q) {
                h_final[b * HID + 2 * tid + q] = hv_[q];
                c_final[b * HID + 2 * tid + q] = creg[q];
            }
        }
    }
}

// ----------------------------------------------------------- launcher ----
extern "C" void kernel_launch(void* const* d_in, const int* in_sizes, int n_in,
                              void* d_out, int out_size, void* d_ws, size_t ws_size,
                              hipStream_t stream) {
    const float* input = (const float*)d_in[0];
    const float* h0    = (const float*)d_in[1];
    const float* c0    = (const float*)d_in[2];
    const float* Wx    = (const float*)d_in[3];
    const float* Wh    = (const float*)d_in[4];
    const float* gn_g  = (const float*)d_in[5];
    const float* gn_b  = (const float*)d_in[6];
    const float* cn_g  = (const float*)d_in[7];
    const float* cn_b  = (const float*)d_in[8];

    char* ws = (char*)d_ws;
    size_t off = 0;
    auto alloc = [&](size_t bytes) -> char* {
        char* p = ws + off;
        off += (bytes + 255) & ~(size_t)255;
        return p;
    };
    u64*  gates_u = (u64*) alloc((size_t)BATCH * GATES * 8);             // 1 MB
    u32*  hx      = (u32*) alloc((size_t)BATCH * HID * 4);               // 128 KB
    u32*  gxsent  = (u32*) alloc((size_t)MTILES * NTILES * 4);           // 8 KB
    bf16* gxT     = (bf16*)alloc((size_t)GATES * (T_STEPS * BATCH) * 2); // 128 MB

    float* outp    = (float*)d_out;
    float* h_final = outp + (size_t)T_STEPS * BATCH * HID;
    float* c_final = h_final + (size_t)BATCH * HID;

    hipLaunchKernelGGL(init_kernel, dim3(256), dim3(256), 0, stream,
                       hx, gates_u, gxsent);

    hipLaunchKernelGGL(fused_kernel, dim3(NSCAN + NGEMM), dim3(512), 0, stream,
                       input, Wx, Wh, h0, c0, gn_g, gn_b, cn_g, cn_b,
                       hx, gates_u, gxT, gxsent, outp, h_final, c_final);
}

// Round 16
// 3333.522 us; speedup vs baseline: 1.3773x; 1.0048x over previous
//
#include <hip/hip_runtime.h>
#include <hip/hip_bf16.h>

typedef __hip_bfloat16 bf16;
typedef __attribute__((ext_vector_type(4))) float f32x4;
typedef __attribute__((ext_vector_type(8))) short bf16x8;
typedef unsigned long long u64;
typedef unsigned short u16;
typedef unsigned u32;

#define T_STEPS 512
#define BATCH   32
#define DIM     1024
#define HID     1024
#define GATES   4096
#define NDOM    4           // independent scan domains (8 batches each)
#define NOWN    32          // owner blocks (1/batch) -- block IDs 0..31
#define NPROD   128         // producer blocks: 4 domains x 32 colgroups
#define NSCAN   (NOWN + NPROD)   // 160 <= 256 worst-case residency
#define MTILES  128         // gemm: 16384 rows / 128
#define NTILES  16          // gemm: 4096 cols / 256
#define NGEMM   (MTILES * NTILES)
#define MAGIC   0x5EED0001u

static __device__ __forceinline__ float sigmf(float x) {
    return 1.0f / (1.0f + __expf(-x));
}
static __device__ __forceinline__ float tanhfast(float x) {
    return 1.0f - 2.0f / (__expf(2.0f * x) + 1.0f);
}

// coherent (LLC-level) helpers
static __device__ __forceinline__ u64 ldc_u64(const u64* p) {
    return __hip_atomic_load((u64*)p, __ATOMIC_RELAXED, __HIP_MEMORY_SCOPE_AGENT);
}
static __device__ __forceinline__ void stc_u64(u64* p, u64 v) {
    __hip_atomic_store(p, v, __ATOMIC_RELAXED, __HIP_MEMORY_SCOPE_AGENT);
}
static __device__ __forceinline__ void stc_u32(u32* p, u32 v) {
    __hip_atomic_store(p, v, __ATOMIC_RELAXED, __HIP_MEMORY_SCOPE_AGENT);
}
static __device__ __forceinline__ u32 ldc_u32(const u32* p) {
    return __hip_atomic_load((u32*)p, __ATOMIC_RELAXED, __HIP_MEMORY_SCOPE_AGENT);
}

// 8 consecutive fp32 -> bf16x8 (RN, same conversion as the old prep path)
static __device__ __forceinline__ bf16x8 cvt8(const float* p) {
    float4 x = *(const float4*)p;
    float4 y = *(const float4*)(p + 4);
    bf16x8 r;
    ((u16*)&r)[0] = __bfloat16_as_ushort(__float2bfloat16(x.x));
    ((u16*)&r)[1] = __bfloat16_as_ushort(__float2bfloat16(x.y));
    ((u16*)&r)[2] = __bfloat16_as_ushort(__float2bfloat16(x.z));
    ((u16*)&r)[3] = __bfloat16_as_ushort(__float2bfloat16(x.w));
    ((u16*)&r)[4] = __bfloat16_as_ushort(__float2bfloat16(y.x));
    ((u16*)&r)[5] = __bfloat16_as_ushort(__float2bfloat16(y.y));
    ((u16*)&r)[6] = __bfloat16_as_ushort(__float2bfloat16(y.z));
    ((u16*)&r)[7] = __bfloat16_as_ushort(__float2bfloat16(y.w));
    return r;
}

// ------------------------------------------------------------ init ----
// Clears ONLY control state (stale tags/sentinels die across replays).
__global__ void init_kernel(u32* __restrict__ hx,
                            u64* __restrict__ gates_u,
                            u32* __restrict__ gxsent) {
    const size_t stride = (size_t)gridDim.x * blockDim.x;
    const size_t t0 = (size_t)blockIdx.x * blockDim.x + threadIdx.x;
    for (size_t i = t0; i < (size_t)BATCH * HID; i += stride) hx[i] = 0xFFFFFFFFu;
    for (size_t i = t0; i < (size_t)BATCH * GATES; i += stride) gates_u[i] = 0;
    for (size_t i = t0; i < (size_t)MTILES * NTILES; i += stride) gxsent[i] = 0u;
}

// ------------------------------------------------------ fused kernel ----
// blocks 0..31   : scan owners (1/batch) -- FIRST in dispatch order.
// blocks 32..159 : scan producers, 4 independent domains of 8 batches.
// blocks 160..   : gemm tiles 128x256, M-major (early t first).
// LDS padded to ~82KB -> 1 block/CU: scan blocks get EXCLUSIVE CUs (no
// SIMD/L1 interference from co-resident gemm blocks); gemm queues on the
// ~96 remaining CUs, still fully overlapped behind the scan.
__global__ __launch_bounds__(512, 2) void fused_kernel(
    const float* __restrict__ input,    // [T*B][1024] fp32
    const float* __restrict__ Wx,       // [4096][1024] fp32
    const float* __restrict__ Wh,       // [4096][1024] fp32
    const float* __restrict__ h0,
    const float* __restrict__ c0,
    const float* __restrict__ gn_g, const float* __restrict__ gn_b,
    const float* __restrict__ cn_g, const float* __restrict__ cn_b,
    u32* __restrict__ hx,               // [B][HID] tagged h (coherent)
    u64* __restrict__ gates_u,          // [B][4096] tagged gates (coherent)
    bf16* __restrict__ gxT,             // [4096 cols][16384 rows] transposed
    u32* __restrict__ gxsent,           // [128][16] tile sentinels
    float* __restrict__ out,
    float* __restrict__ h_final,
    float* __restrict__ c_final) {

    const int tid  = threadIdx.x;
    const int lane = tid & 63;
    const int w    = tid >> 6;           // 0..7

    // occupancy limiter: forces 1 block/CU (82KB > 160KB/2). One dummy
    // store keeps it allocated; blockIdx guard defeats DCE.
    __shared__ char ldspad[66 * 1024];
    if (blockIdx.x == 0xFFFFFFFFu) ldspad[tid] = 1;

    if (blockIdx.x >= NSCAN) {
        // ========================= GEMM BLOCK =========================
        const int gid = blockIdx.x - NSCAN;
        const int bm = gid >> 4;         // M-major: low blockIdx = low t
        const int bn = gid & 15;
        const int wm = (w >> 2) * 64, wn = (w & 3) * 64;
        const int lr = lane & 15;
        const int ko = (lane >> 4) * 8;

        const float* Af = input + (size_t)(bm * 128 + wm + lr) * DIM + ko;
        const float* Bf = Wx    + (size_t)(bn * 256 + wn + lr) * DIM + ko;

        f32x4 acc[4][4] = {};
        for (int k = 0; k < DIM; k += 32) {
            bf16x8 af[4], bw[4];
#pragma unroll
            for (int m = 0; m < 4; ++m)
                af[m] = cvt8(Af + (size_t)m * 16 * DIM + k);
#pragma unroll
            for (int n = 0; n < 4; ++n)
                bw[n] = cvt8(Bf + (size_t)n * 16 * DIM + k);
#pragma unroll
            for (int m = 0; m < 4; ++m)
#pragma unroll
                for (int n = 0; n < 4; ++n)
                    acc[m][n] = __builtin_amdgcn_mfma_f32_16x16x32_bf16(af[m], bw[n], acc[m][n], 0, 0, 0);
        }
        const int cr = (lane >> 4) * 4;
        u64* gxT64 = (u64*)gxT;
#pragma unroll
        for (int m = 0; m < 4; ++m)
#pragma unroll
            for (int n = 0; n < 4; ++n) {
                int col = bn * 256 + wn + n * 16 + lr;
                int rb  = bm * 128 + wm + m * 16 + cr;   // 4-aligned
                u64 pk = 0;
#pragma unroll
                for (int r = 0; r < 4; ++r)
                    pk |= (u64)__bfloat16_as_ushort(__float2bfloat16(acc[m][n][r])) << (16 * r);
                stc_u64(gxT64 + (size_t)col * 4096 + (rb >> 2), pk);
            }
        asm volatile("s_waitcnt vmcnt(0)" ::: "memory");
        __syncthreads();                 // all tile stores LLC-acked
        if (tid == 0) stc_u32(gxsent + bm * NTILES + bn, MAGIC);
        return;
    }

    if (blockIdx.x >= NOWN) {
        // ======================= PRODUCER BLOCK =======================
        const int pid  = blockIdx.x - NOWN;
        const int d    = pid & 3;            // domain: batches 8d..8d+7
        const int g    = pid >> 2;           // 0..31: gate cols [g*128,+128)
        const int ni   = g * 8 + w;          // this wave's 16-col tile
        const int lr   = lane & 15;
        const int hi   = lane >> 4;
        const int ko   = hi * 8;
        const int gcol = ni * 16 + lr;

        __shared__ __align__(16) char hsm[8 * 2048];  // 8 rows x 1024 bf16, swizzled

        // self-convert this wave's Wh slice (16 cols x 1024 K) into VGPRs
        const float* wf = Wh + (size_t)gcol * DIM + ko;
        bf16x8 bfrag[32];
#pragma unroll
        for (int kk = 0; kk < 32; ++kk)
            bfrag[kk] = cvt8(wf + kk * 32);

        const int arow = (lr & 7) * 2048;      // A row m -> staged row m&7
        const int axor = (lr & 7) << 4;

        const u64* gxT64 = (const u64*)gxT;
        const int ntile = g >> 1;
        u16 gxu[4];
        // gx fetch for t=0: sentinel then one u64 (4 batch rows for this hi)
        {
            u32 sv = ldc_u32(gxsent + 0 * NTILES + ntile);   // rows 8d..8d+7 in tile 0
            while (sv != MAGIC) {
                __builtin_amdgcn_s_sleep(2);
                sv = ldc_u32(gxsent + 0 * NTILES + ntile);
            }
            u64 v = ldc_u64(gxT64 + (size_t)gcol * 4096 + 2 * d + (hi & 1));
            gxu[0] = (u16)v; gxu[1] = (u16)(v >> 16);
            gxu[2] = (u16)(v >> 32); gxu[3] = (u16)(v >> 48);
        }

        for (int t = 0; t < T_STEPS; ++t) {
            // ---- stage 8 h rows (tag == t): wave w stages row w ----
            {
                const u64* hsrc = (const u64*)(hx + (size_t)(8 * d + w) * HID);
                char* drow = hsm + w * 2048;
                const int sx = w << 4;
                const u32 want = (u32)t;
                u64 vv[8];
#pragma unroll
                for (int k = 0; k < 8; ++k)
                    vv[k] = ldc_u64(hsrc + k * 64 + lane);   // 8 loads in flight
                for (;;) {
                    bool ok = true;
#pragma unroll
                    for (int k = 0; k < 8; ++k) {
                        if ((((u32)(vv[k] >> 16) & 0xFFFFu) != want) ||
                            ((u32)(vv[k] >> 48) != want)) {
                            ok = false;
                            vv[k] = ldc_u64(hsrc + k * 64 + lane);
                        }
                    }
                    if (ok) break;
                    __builtin_amdgcn_s_sleep(0);   // exclusive CU: spin hard
                }
#pragma unroll
                for (int k = 0; k < 8; ++k) {
                    int j = k * 64 + lane;       // pair index 0..511
                    u32 packed = (u32)(vv[k] & 0xFFFFu) |
                                 (((u32)(vv[k] >> 32) & 0xFFFFu) << 16);
                    *(u32*)(drow + ((4 * j) ^ sx)) = packed;
                }
            }
            __syncthreads();   // couples this block to only 8 owners

            // ---- MFMA (A rows duplicate mod 8) + publish 8 valid D rows ----
            {
                f32x4 acc = {0.f, 0.f, 0.f, 0.f};
#pragma unroll
                for (int kk = 0; kk < 32; ++kk) {
                    bf16x8 a = *(const bf16x8*)(hsm + arow + ((kk * 64 + ko * 2) ^ axor));
                    acc = __builtin_amdgcn_mfma_f32_16x16x32_bf16(a, bfrag[kk], acc, 0, 0, 0);
                }
                if (hi < 2) {                    // D rows 0..7 = batches 8d..8d+7
                    u64* gp = gates_u + (size_t)(8 * d + hi * 4) * GATES + gcol;
                    const u64 tagup = (u64)(u32)(t + 1) << 32;
#pragma unroll
                    for (int r = 0; r < 4; ++r) {
                        union { u16 u; bf16 h; } cv; cv.u = gxu[r];
                        float val = acc[r] + __bfloat162float(cv.h);
                        stc_u64(gp + (size_t)r * GATES, tagup | (u64)__float_as_uint(val));
                    }
                }
            }

            // ---- prefetch gx(t+1) (overlaps next h-poll) ----
            if (t + 1 < T_STEPS) {
                int tn = t + 1;
                int mtile = (4 * tn + d) >> 4;   // (tn*32 + 8d) >> 7
                u32 sv = ldc_u32(gxsent + mtile * NTILES + ntile);
                while (sv != MAGIC) {
                    __builtin_amdgcn_s_sleep(2);
                    sv = ldc_u32(gxsent + mtile * NTILES + ntile);
                }
                u64 v = ldc_u64(gxT64 + (size_t)gcol * 4096 + tn * 8 + 2 * d + (hi & 1));
                gxu[0] = (u16)v; gxu[1] = (u16)(v >> 16);
                gxu[2] = (u16)(v >> 32); gxu[3] = (u16)(v >> 48);
            }
            // no end barrier: dataflow (h(t+1) tags) subsumes it
        }
        return;
    }

    // ========================== OWNER BLOCK ==========================
    const int b = blockIdx.x;             // batch 0..31 (lowest block IDs)
    __shared__ float red[2][8];
    __shared__ float redc[2][8];          // separate buffer: saves a barrier

    float creg[2];
#pragma unroll
    for (int q = 0; q < 2; ++q) creg[q] = c0[b * HID + 2 * tid + q];

    // startup: publish tagged h0 (tag 0) -- init left 0xFFFF in tag fields
    {
        u32 e0 = (u32)__bfloat16_as_ushort(__float2bfloat16(h0[b * HID + 2 * tid]));
        u32 e1 = (u32)__bfloat16_as_ushort(__float2bfloat16(h0[b * HID + 2 * tid + 1]));
        stc_u64((u64*)(hx + (size_t)b * HID + 2 * tid), (u64)e0 | ((u64)e1 << 32));
    }

    for (int t = 0; t < T_STEPS; ++t) {
        // ---- poll own tagged gates direct-to-register ----
        const u64* grow = gates_u + (size_t)b * GATES;
        const u32 want = (u32)(t + 1);
        u64 vg[4][2];
#pragma unroll
        for (int q = 0; q < 4; ++q)
#pragma unroll
            for (int e = 0; e < 2; ++e)
                vg[q][e] = ldc_u64(grow + q * 1024 + 2 * tid + e);
        for (;;) {
            bool ok = true;
#pragma unroll
            for (int q = 0; q < 4; ++q)
#pragma unroll
            for (int e = 0; e < 2; ++e)
                if ((u32)(vg[q][e] >> 32) != want) {
                    ok = false;
                    vg[q][e] = ldc_u64(grow + q * 1024 + 2 * tid + e);
                }
            if (ok) break;
            __builtin_amdgcn_s_sleep(0);   // exclusive CU: spin hard
        }
        float gv[4][2];
        float s = 0.f, s2 = 0.f;
#pragma unroll
        for (int q = 0; q < 4; ++q)
#pragma unroll
            for (int e = 0; e < 2; ++e) {
                float x = __uint_as_float((u32)vg[q][e]);
                gv[q][e] = x;
                s += x; s2 += x * x;
            }
#pragma unroll
        for (int off = 32; off > 0; off >>= 1) {
            s  += __shfl_down(s, off, 64);
            s2 += __shfl_down(s2, off, 64);
        }
        if (lane == 0) { red[0][w] = s; red[1][w] = s2; }
        __syncthreads();   // barrier 1
        s  = red[0][0] + red[0][1] + red[0][2] + red[0][3]
           + red[0][4] + red[0][5] + red[0][6] + red[0][7];
        s2 = red[1][0] + red[1][1] + red[1][2] + red[1][3]
           + red[1][4] + red[1][5] + red[1][6] + red[1][7];
        const float mu   = s * (1.0f / GATES);
        const float rstd = rsqrtf(s2 * (1.0f / GATES) - mu * mu + 1e-5f);

        float ov[2], cn_[2];
        float cs = 0.f, cs2 = 0.f;
#pragma unroll
        for (int q = 0; q < 2; ++q) {
            int j = 2 * tid + q;
            float iv = sigmf(   (gv[0][q] - mu) * rstd * gn_g[j]           + gn_b[j]);
            float fv = sigmf(   (gv[1][q] - mu) * rstd * gn_g[HID + j]     + gn_b[HID + j]);
            float gg = tanhfast((gv[2][q] - mu) * rstd * gn_g[2 * HID + j] + gn_b[2 * HID + j]);
            ov[q] =             (gv[3][q] - mu) * rstd * gn_g[3 * HID + j] + gn_b[3 * HID + j];
            float cnew = fv * creg[q] + iv * gg;
            cn_[q] = cnew;
            cs += cnew; cs2 += cnew * cnew;
        }
#pragma unroll
        for (int off = 32; off > 0; off >>= 1) {
            cs  += __shfl_down(cs, off, 64);
            cs2 += __shfl_down(cs2, off, 64);
        }
        if (lane == 0) { redc[0][w] = cs; redc[1][w] = cs2; }
        __syncthreads();   // barrier 2
        cs  = redc[0][0] + redc[0][1] + redc[0][2] + redc[0][3]
            + redc[0][4] + redc[0][5] + redc[0][6] + redc[0][7];
        cs2 = redc[1][0] + redc[1][1] + redc[1][2] + redc[1][3]
            + redc[1][4] + redc[1][5] + redc[1][6] + redc[1][7];
        const float mu2   = cs * (1.0f / HID);
        const float rstd2 = rsqrtf(cs2 * (1.0f / HID) - mu2 * mu2 + 1e-5f);

        // c-LN, h; publish tagged h immediately (self-flagging)
        float hv_[2];
        u32 he[2];
#pragma unroll
        for (int q = 0; q < 2; ++q) {
            float cn = (cn_[q] - mu2) * rstd2 * cn_g[2 * tid + q] + cn_b[2 * tid + q];
            creg[q] = cn;
            hv_[q] = sigmf(ov[q]) * tanhfast(cn);
            he[q] = ((u32)(t + 1) << 16) |
                    (u32)__bfloat16_as_ushort(__float2bfloat16(hv_[q]));
        }
        stc_u64((u64*)(hx + (size_t)b * HID + 2 * tid),
                (u64)he[0] | ((u64)he[1] << 32));

        // deferred: out (NT) and finals -- off the critical path
        float* orow = out + ((size_t)t * BATCH + b) * HID + 2 * tid;
#pragma unroll
        for (int q = 0; q < 2; ++q)
            __builtin_nontemporal_store(hv_[q], orow + q);
        if (t == T_STEPS - 1) {
#pragma unroll
            for (int q = 0; q < 2; ++q) {
                h_final[b * HID + 2 * tid + q] = hv_[q];
                c_final[b * HID + 2 * tid + q] = creg[q];
            }
        }
    }
}

// ----------------------------------------------------------- launcher ----
extern "C" void kernel_launch(void* const* d_in, const int* in_sizes, int n_in,
                              void* d_out, int out_size, void* d_ws, size_t ws_size,
                              hipStream_t stream) {
    const float* input = (const float*)d_in[0];
    const float* h0    = (const float*)d_in[1];
    const float* c0    = (const float*)d_in[2];
    const float* Wx    = (const float*)d_in[3];
    const float* Wh    = (const float*)d_in[4];
    const float* gn_g  = (const float*)d_in[5];
    const float* gn_b  = (const float*)d_in[6];
    const float* cn_g  = (const float*)d_in[7];
    const float* cn_b  = (const float*)d_in[8];

    char* ws = (char*)d_ws;
    size_t off = 0;
    auto alloc = [&](size_t bytes) -> char* {
        char* p = ws + off;
        off += (bytes + 255) & ~(size_t)255;
        return p;
    };
    u64*  gates_u = (u64*) alloc((size_t)BATCH * GATES * 8);             // 1 MB
    u32*  hx      = (u32*) alloc((size_t)BATCH * HID * 4);               // 128 KB
    u32*  gxsent  = (u32*) alloc((size_t)MTILES * NTILES * 4);           // 8 KB
    bf16* gxT     = (bf16*)alloc((size_t)GATES * (T_STEPS * BATCH) * 2); // 128 MB

    float* outp    = (float*)d_out;
    float* h_final = outp + (size_t)T_STEPS * BATCH * HID;
    float* c_final = h_final + (size_t)BATCH * HID;

    hipLaunchKernelGGL(init_kernel, dim3(256), dim3(256), 0, stream,
                       hx, gates_u, gxsent);

    hipLaunchKernelGGL(fused_kernel, dim3(NSCAN + NGEMM), dim3(512), 0, stream,
                       input, Wx, Wh, h0, c0, gn_g, gn_b, cn_g, cn_b,
                       hx, gates_u, gxT, gxsent, outp, h_final, c_final);
}

// Round 17
// 3323.045 us; speedup vs baseline: 1.3817x; 1.0032x over previous
//
#include <hip/hip_runtime.h>
#include <hip/hip_bf16.h>

typedef __hip_bfloat16 bf16;
typedef __attribute__((ext_vector_type(4))) float f32x4;
typedef __attribute__((ext_vector_type(8))) short bf16x8;
typedef unsigned long long u64;
typedef unsigned short u16;
typedef unsigned u32;

#define T_STEPS 512
#define BATCH   32
#define DIM     1024
#define HID     1024
#define GATES   4096
#define NDOM    4           // independent scan domains (8 batches each)
#define NOWN    32          // owner blocks (1/batch) -- block IDs 0..31
#define NPROD   128         // producer blocks: 4 domains x 32 colgroups
#define NSCAN   (NOWN + NPROD)   // 160 <= 256 worst-case residency
#define MTILES  128         // gemm: 16384 rows / 128
#define NTILES  16          // gemm: 4096 cols / 256
#define NGEMM   (MTILES * NTILES)
#define MAGIC   0x5EED0001u

static __device__ __forceinline__ float sigmf(float x) {
    return 1.0f / (1.0f + __expf(-x));
}
static __device__ __forceinline__ float tanhfast(float x) {
    return 1.0f - 2.0f / (__expf(2.0f * x) + 1.0f);
}

// coherent (LLC-level) helpers
static __device__ __forceinline__ u64 ldc_u64(const u64* p) {
    return __hip_atomic_load((u64*)p, __ATOMIC_RELAXED, __HIP_MEMORY_SCOPE_AGENT);
}
static __device__ __forceinline__ void stc_u64(u64* p, u64 v) {
    __hip_atomic_store(p, v, __ATOMIC_RELAXED, __HIP_MEMORY_SCOPE_AGENT);
}
static __device__ __forceinline__ void stc_u32(u32* p, u32 v) {
    __hip_atomic_store(p, v, __ATOMIC_RELAXED, __HIP_MEMORY_SCOPE_AGENT);
}
static __device__ __forceinline__ u32 ldc_u32(const u32* p) {
    return __hip_atomic_load((u32*)p, __ATOMIC_RELAXED, __HIP_MEMORY_SCOPE_AGENT);
}

// 8 consecutive fp32 -> bf16x8 (RN, same conversion as the old prep path)
static __device__ __forceinline__ bf16x8 cvt8(const float* p) {
    float4 x = *(const float4*)p;
    float4 y = *(const float4*)(p + 4);
    bf16x8 r;
    ((u16*)&r)[0] = __bfloat16_as_ushort(__float2bfloat16(x.x));
    ((u16*)&r)[1] = __bfloat16_as_ushort(__float2bfloat16(x.y));
    ((u16*)&r)[2] = __bfloat16_as_ushort(__float2bfloat16(x.z));
    ((u16*)&r)[3] = __bfloat16_as_ushort(__float2bfloat16(x.w));
    ((u16*)&r)[4] = __bfloat16_as_ushort(__float2bfloat16(y.x));
    ((u16*)&r)[5] = __bfloat16_as_ushort(__float2bfloat16(y.y));
    ((u16*)&r)[6] = __bfloat16_as_ushort(__float2bfloat16(y.z));
    ((u16*)&r)[7] = __bfloat16_as_ushort(__float2bfloat16(y.w));
    return r;
}

// ------------------------------------------------------------ init ----
// Clears ONLY control state (stale tags/sentinels die across replays).
__global__ void init_kernel(u32* __restrict__ hx,
                            u64* __restrict__ gates_u,
                            u32* __restrict__ gxsent) {
    const size_t stride = (size_t)gridDim.x * blockDim.x;
    const size_t t0 = (size_t)blockIdx.x * blockDim.x + threadIdx.x;
    for (size_t i = t0; i < (size_t)BATCH * HID; i += stride) hx[i] = 0xFFFFFFFFu;
    for (size_t i = t0; i < (size_t)BATCH * GATES; i += stride) gates_u[i] = 0;
    for (size_t i = t0; i < (size_t)MTILES * NTILES; i += stride) gxsent[i] = 0u;
}

// ------------------------------------------------------ fused kernel ----
// blocks 0..31   : scan owners (1/batch) -- FIRST in dispatch order.
// blocks 32..159 : scan producers, 4 independent domains of 8 batches.
// blocks 160..   : gemm tiles 128x256, M-major (early t first).
// VOLATILE LDS pad (~83KB total) -> 1 block/CU GUARANTEED: scan blocks get
// exclusive CUs (no SIMD/L1/LLC-port interference from co-resident gemm);
// gemm queues on the ~96 remaining CUs, still overlapped behind the scan.
// (r16's pad was DCE'd -- volatile accesses cannot be removed.)
__global__ __launch_bounds__(512, 2) void fused_kernel(
    const float* __restrict__ input,    // [T*B][1024] fp32
    const float* __restrict__ Wx,       // [4096][1024] fp32
    const float* __restrict__ Wh,       // [4096][1024] fp32
    const float* __restrict__ h0,
    const float* __restrict__ c0,
    const float* __restrict__ gn_g, const float* __restrict__ gn_b,
    const float* __restrict__ cn_g, const float* __restrict__ cn_b,
    u32* __restrict__ hx,               // [B][HID] tagged h (coherent)
    u64* __restrict__ gates_u,          // [B][4096] tagged gates (coherent)
    bf16* __restrict__ gxT,             // [4096 cols][16384 rows] transposed
    u32* __restrict__ gxsent,           // [128][16] tile sentinels
    float* __restrict__ out,
    float* __restrict__ h_final,
    float* __restrict__ c_final) {

    const int tid  = threadIdx.x;
    const int lane = tid & 63;
    const int w    = tid >> 6;           // 0..7

    // occupancy limiter: 66KB volatile pad + ~16.5KB live LDS > 80KB
    // forces 1 block/CU. Volatile accesses below are unreachable at
    // runtime but CANNOT be DCE'd, so the array must be allocated.
    volatile __shared__ char ldspad[66 * 1024];
    if (blockIdx.x == 0xFFFFFFFFu) {
        ldspad[tid] = (char)tid;
        if (ldspad[(tid + 1) & 1023])
            stc_u32((u32*)out, 1u);      // observable side effect
    }

    if (blockIdx.x >= NSCAN) {
        // ========================= GEMM BLOCK =========================
        const int gid = blockIdx.x - NSCAN;
        const int bm = gid >> 4;         // M-major: low blockIdx = low t
        const int bn = gid & 15;
        const int wm = (w >> 2) * 64, wn = (w & 3) * 64;
        const int lr = lane & 15;
        const int ko = (lane >> 4) * 8;

        const float* Af = input + (size_t)(bm * 128 + wm + lr) * DIM + ko;
        const float* Bf = Wx    + (size_t)(bn * 256 + wn + lr) * DIM + ko;

        f32x4 acc[4][4] = {};
        for (int k = 0; k < DIM; k += 32) {
            bf16x8 af[4], bw[4];
#pragma unroll
            for (int m = 0; m < 4; ++m)
                af[m] = cvt8(Af + (size_t)m * 16 * DIM + k);
#pragma unroll
            for (int n = 0; n < 4; ++n)
                bw[n] = cvt8(Bf + (size_t)n * 16 * DIM + k);
#pragma unroll
            for (int m = 0; m < 4; ++m)
#pragma unroll
                for (int n = 0; n < 4; ++n)
                    acc[m][n] = __builtin_amdgcn_mfma_f32_16x16x32_bf16(af[m], bw[n], acc[m][n], 0, 0, 0);
        }
        const int cr = (lane >> 4) * 4;
        u64* gxT64 = (u64*)gxT;
#pragma unroll
        for (int m = 0; m < 4; ++m)
#pragma unroll
            for (int n = 0; n < 4; ++n) {
                int col = bn * 256 + wn + n * 16 + lr;
                int rb  = bm * 128 + wm + m * 16 + cr;   // 4-aligned
                u64 pk = 0;
#pragma unroll
                for (int r = 0; r < 4; ++r)
                    pk |= (u64)__bfloat16_as_ushort(__float2bfloat16(acc[m][n][r])) << (16 * r);
                stc_u64(gxT64 + (size_t)col * 4096 + (rb >> 2), pk);
            }
        asm volatile("s_waitcnt vmcnt(0)" ::: "memory");
        __syncthreads();                 // all tile stores LLC-acked
        if (tid == 0) stc_u32(gxsent + bm * NTILES + bn, MAGIC);
        return;
    }

    if (blockIdx.x >= NOWN) {
        // ======================= PRODUCER BLOCK =======================
        const int pid  = blockIdx.x - NOWN;
        const int d    = pid & 3;            // domain: batches 8d..8d+7
        const int g    = pid >> 2;           // 0..31: gate cols [g*128,+128)
        const int ni   = g * 8 + w;          // this wave's 16-col tile
        const int lr   = lane & 15;
        const int hi   = lane >> 4;
        const int ko   = hi * 8;
        const int gcol = ni * 16 + lr;

        __shared__ __align__(16) char hsm[8 * 2048];  // 8 rows x 1024 bf16, swizzled

        // self-convert this wave's Wh slice (16 cols x 1024 K) into VGPRs
        const float* wf = Wh + (size_t)gcol * DIM + ko;
        bf16x8 bfrag[32];
#pragma unroll
        for (int kk = 0; kk < 32; ++kk)
            bfrag[kk] = cvt8(wf + kk * 32);

        const int arow = (lr & 7) * 2048;      // A row m -> staged row m&7
        const int axor = (lr & 7) << 4;

        const u64* gxT64 = (const u64*)gxT;
        const int ntile = g >> 1;
        u16 gxu[4];
        // gx fetch for t=0: sentinel then one u64 (4 batch rows for this hi)
        {
            u32 sv = ldc_u32(gxsent + 0 * NTILES + ntile);   // rows 8d..8d+7 in tile 0
            while (sv != MAGIC) {
                __builtin_amdgcn_s_sleep(2);
                sv = ldc_u32(gxsent + 0 * NTILES + ntile);
            }
            u64 v = ldc_u64(gxT64 + (size_t)gcol * 4096 + 2 * d + (hi & 1));
            gxu[0] = (u16)v; gxu[1] = (u16)(v >> 16);
            gxu[2] = (u16)(v >> 32); gxu[3] = (u16)(v >> 48);
        }

        for (int t = 0; t < T_STEPS; ++t) {
            // ---- stage 8 h rows (tag == t): wave w stages row w ----
            {
                const u64* hsrc = (const u64*)(hx + (size_t)(8 * d + w) * HID);
                char* drow = hsm + w * 2048;
                const int sx = w << 4;
                const u32 want = (u32)t;
                u64 vv[8];
#pragma unroll
                for (int k = 0; k < 8; ++k)
                    vv[k] = ldc_u64(hsrc + k * 64 + lane);   // 8 loads in flight
                for (;;) {
                    bool ok = true;
#pragma unroll
                    for (int k = 0; k < 8; ++k) {
                        if ((((u32)(vv[k] >> 16) & 0xFFFFu) != want) ||
                            ((u32)(vv[k] >> 48) != want)) {
                            ok = false;
                            vv[k] = ldc_u64(hsrc + k * 64 + lane);
                        }
                    }
                    if (ok) break;
                    __builtin_amdgcn_s_sleep(0);   // exclusive CU: spin hard
                }
#pragma unroll
                for (int k = 0; k < 8; ++k) {
                    int j = k * 64 + lane;       // pair index 0..511
                    u32 packed = (u32)(vv[k] & 0xFFFFu) |
                                 (((u32)(vv[k] >> 32) & 0xFFFFu) << 16);
                    *(u32*)(drow + ((4 * j) ^ sx)) = packed;
                }
            }
            __syncthreads();   // couples this block to only 8 owners

            // ---- MFMA (A rows duplicate mod 8) + publish 8 valid D rows ----
            {
                f32x4 acc = {0.f, 0.f, 0.f, 0.f};
#pragma unroll
                for (int kk = 0; kk < 32; ++kk) {
                    bf16x8 a = *(const bf16x8*)(hsm + arow + ((kk * 64 + ko * 2) ^ axor));
                    acc = __builtin_amdgcn_mfma_f32_16x16x32_bf16(a, bfrag[kk], acc, 0, 0, 0);
                }
                if (hi < 2) {                    // D rows 0..7 = batches 8d..8d+7
                    u64* gp = gates_u + (size_t)(8 * d + hi * 4) * GATES + gcol;
                    const u64 tagup = (u64)(u32)(t + 1) << 32;
#pragma unroll
                    for (int r = 0; r < 4; ++r) {
                        union { u16 u; bf16 h; } cv; cv.u = gxu[r];
                        float val = acc[r] + __bfloat162float(cv.h);
                        stc_u64(gp + (size_t)r * GATES, tagup | (u64)__float_as_uint(val));
                    }
                }
            }

            // ---- prefetch gx(t+1) (overlaps next h-poll) ----
            if (t + 1 < T_STEPS) {
                int tn = t + 1;
                int mtile = (4 * tn + d) >> 4;   // (tn*32 + 8d) >> 7
                u32 sv = ldc_u32(gxsent + mtile * NTILES + ntile);
                while (sv != MAGIC) {
                    __builtin_amdgcn_s_sleep(2);
                    sv = ldc_u32(gxsent + mtile * NTILES + ntile);
                }
                u64 v = ldc_u64(gxT64 + (size_t)gcol * 4096 + tn * 8 + 2 * d + (hi & 1));
                gxu[0] = (u16)v; gxu[1] = (u16)(v >> 16);
                gxu[2] = (u16)(v >> 32); gxu[3] = (u16)(v >> 48);
            }
            // no end barrier: dataflow (h(t+1) tags) subsumes it
        }
        return;
    }

    // ========================== OWNER BLOCK ==========================
    const int b = blockIdx.x;             // batch 0..31 (lowest block IDs)
    __shared__ float red[2][8];
    __shared__ float redc[2][8];          // separate buffer: saves a barrier

    float creg[2];
#pragma unroll
    for (int q = 0; q < 2; ++q) creg[q] = c0[b * HID + 2 * tid + q];

    // startup: publish tagged h0 (tag 0) -- init left 0xFFFF in tag fields
    {
        u32 e0 = (u32)__bfloat16_as_ushort(__float2bfloat16(h0[b * HID + 2 * tid]));
        u32 e1 = (u32)__bfloat16_as_ushort(__float2bfloat16(h0[b * HID + 2 * tid + 1]));
        stc_u64((u64*)(hx + (size_t)b * HID + 2 * tid), (u64)e0 | ((u64)e1 << 32));
    }

    for (int t = 0; t < T_STEPS; ++t) {
        // ---- poll own tagged gates direct-to-register ----
        const u64* grow = gates_u + (size_t)b * GATES;
        const u32 want = (u32)(t + 1);
        u64 vg[4][2];
#pragma unroll
        for (int q = 0; q < 4; ++q)
#pragma unroll
            for (int e = 0; e < 2; ++e)
                vg[q][e] = ldc_u64(grow + q * 1024 + 2 * tid + e);
        for (;;) {
            bool ok = true;
#pragma unroll
            for (int q = 0; q < 4; ++q)
#pragma unroll
            for (int e = 0; e < 2; ++e)
                if ((u32)(vg[q][e] >> 32) != want) {
                    ok = false;
                    vg[q][e] = ldc_u64(grow + q * 1024 + 2 * tid + e);
                }
            if (ok) break;
            __builtin_amdgcn_s_sleep(0);   // exclusive CU: spin hard
        }
        float gv[4][2];
        float s = 0.f, s2 = 0.f;
#pragma unroll
        for (int q = 0; q < 4; ++q)
#pragma unroll
            for (int e = 0; e < 2; ++e) {
                float x = __uint_as_float((u32)vg[q][e]);
                gv[q][e] = x;
                s += x; s2 += x * x;
            }
#pragma unroll
        for (int off = 32; off > 0; off >>= 1) {
            s  += __shfl_down(s, off, 64);
            s2 += __shfl_down(s2, off, 64);
        }
        if (lane == 0) { red[0][w] = s; red[1][w] = s2; }
        __syncthreads();   // barrier 1
        s  = red[0][0] + red[0][1] + red[0][2] + red[0][3]
           + red[0][4] + red[0][5] + red[0][6] + red[0][7];
        s2 = red[1][0] + red[1][1] + red[1][2] + red[1][3]
           + red[1][4] + red[1][5] + red[1][6] + red[1][7];
        const float mu   = s * (1.0f / GATES);
        const float rstd = rsqrtf(s2 * (1.0f / GATES) - mu * mu + 1e-5f);

        float ov[2], cn_[2];
        float cs = 0.f, cs2 = 0.f;
#pragma unroll
        for (int q = 0; q < 2; ++q) {
            int j = 2 * tid + q;
            float iv = sigmf(   (gv[0][q] - mu) * rstd * gn_g[j]           + gn_b[j]);
            float fv = sigmf(   (gv[1][q] - mu) * rstd * gn_g[HID + j]     + gn_b[HID + j]);
            float gg = tanhfast((gv[2][q] - mu) * rstd * gn_g[2 * HID + j] + gn_b[2 * HID + j]);
            ov[q] =             (gv[3][q] - mu) * rstd * gn_g[3 * HID + j] + gn_b[3 * HID + j];
            float cnew = fv * creg[q] + iv * gg;
            cn_[q] = cnew;
            cs += cnew; cs2 += cnew * cnew;
        }
#pragma unroll
        for (int off = 32; off > 0; off >>= 1) {
            cs  += __shfl_down(cs, off, 64);
            cs2 += __shfl_down(cs2, off, 64);
        }
        if (lane == 0) { redc[0][w] = cs; redc[1][w] = cs2; }
        __syncthreads();   // barrier 2
        cs  = redc[0][0] + redc[0][1] + redc[0][2] + redc[0][3]
            + redc[0][4] + redc[0][5] + redc[0][6] + redc[0][7];
        cs2 = redc[1][0] + redc[1][1] + redc[1][2] + redc[1][3]
            + redc[1][4] + redc[1][5] + redc[1][6] + redc[1][7];
        const float mu2   = cs * (1.0f / HID);
        const float rstd2 = rsqrtf(cs2 * (1.0f / HID) - mu2 * mu2 + 1e-5f);

        // c-LN, h; publish tagged h immediately (self-flagging)
        float hv_[2];
        u32 he[2];
#pragma unroll
        for (int q = 0; q < 2; ++q) {
            float cn = (cn_[q] - mu2) * rstd2 * cn_g[2 * tid + q] + cn_b[2 * tid + q];
            creg[q] = cn;
            hv_[q] = sigmf(ov[q]) * tanhfast(cn);
            he[q] = ((u32)(t + 1) << 16) |
                    (u32)__bfloat16_as_ushort(__float2bfloat16(hv_[q]));
        }
        stc_u64((u64*)(hx + (size_t)b * HID + 2 * tid),
                (u64)he[0] | ((u64)he[1] << 32));

        // deferred: out (NT) and finals -- off the critical path
        float* orow = out + ((size_t)t * BATCH + b) * HID + 2 * tid;
#pragma unroll
        for (int q = 0; q < 2; ++q)
            __builtin_nontemporal_store(hv_[q], orow + q);
        if (t == T_STEPS - 1) {
#pragma unroll
            for (int q = 0; q < 2; ++q) {
                h_final[b * HID + 2 * tid + q] = hv_[q];
                c_final[b * HID + 2 * tid + q] = creg[q];
            }
        }
    }
}

// ----------------------------------------------------------- launcher ----
extern "C" void kernel_launch(void* const* d_in, const int* in_sizes, int n_in,
                              void* d_out, int out_size, void* d_ws, size_t ws_size,
                              hipStream_t stream) {
    const float* input = (const float*)d_in[0];
    const float* h0    = (const float*)d_in[1];
    const float* c0    = (const float*)d_in[2];
    const float* Wx    = (const float*)d_in[3];
    const float* Wh    = (const float*)d_in[4];
    const float* gn_g  = (const float*)d_in[5];
    const float* gn_b  = (const float*)d_in[6];
    const float* cn_g  = (const float*)d_in[7];
    const float* cn_b  = (const float*)d_in[8];

    char* ws = (char*)d_ws;
    size_t off = 0;
    auto alloc = [&](size_t bytes) -> char* {
        char* p = ws + off;
        off += (bytes + 255) & ~(size_t)255;
        return p;
    };
    u64*  gates_u = (u64*) alloc((size_t)BATCH * GATES * 8);             // 1 MB
    u32*  hx      = (u32*) alloc((size_t)BATCH * HID * 4);               // 128 KB
    u32*  gxsent  = (u32*) alloc((size_t)MTILES * NTILES * 4);           // 8 KB
    bf16* gxT     = (bf16*)alloc((size_t)GATES * (T_STEPS * BATCH) * 2); // 128 MB

    float* outp    = (float*)d_out;
    float* h_final = outp + (size_t)T_STEPS * BATCH * HID;
    float* c_final = h_final + (size_t)BATCH * HID;

    hipLaunchKernelGGL(init_kernel, dim3(256), dim3(256), 0, stream,
                       hx, gates_u, gxsent);

    hipLaunchKernelGGL(fused_kernel, dim3(NSCAN + NGEMM), dim3(512), 0, stream,
                       input, Wx, Wh, h0, c0, gn_g, gn_b, cn_g, cn_b,
                       hx, gates_u, gxT, gxsent, outp, h_final, c_final);
}